// Round 13
// baseline (360.684 us; speedup 1.0000x reference)
//
#include <hip/hip_runtime.h>
#include <math.h>

// Problem constants: N=50000, E=800000, IN=128, OUT=64, H1=2, H2=1
#define NNODES 50000
#define NEDGES 800000
#define NRANGE 6250          // NNODES / 8 (one dst-range per XCD)

// ---- manual bf16 pack/unpack (plain uint words) ----
__device__ __forceinline__ unsigned bfpack(float a, float b) {
    unsigned ua = __float_as_uint(a), ub = __float_as_uint(b);
    ua = (ua + 0x7fffu + ((ua >> 16) & 1u)) >> 16;
    ub = (ub + 0x7fffu + ((ub >> 16) & 1u)) >> 16;
    return ua | (ub << 16);
}
__device__ __forceinline__ float bflo(unsigned u) { return __uint_as_float(u << 16); }
__device__ __forceinline__ float bfhi(unsigned u) { return __uint_as_float(u & 0xffff0000u); }

// ---------------- CSR build (by dst; shared by both layers) ----------------

__global__ __launch_bounds__(256) void hist_kernel(const int* __restrict__ dst,
                                                   int* __restrict__ deg) {
    int e = blockIdx.x * 256 + threadIdx.x;
    if (e < NEDGES) atomicAdd(&deg[dst[e]], 1);
}

// row allocation WITHOUT global scan: wave-local shfl scan + 1 atomic/wave.
// Row order != node order (harmless: each row is still contiguous).
__global__ __launch_bounds__(256) void alloc_kernel(const int* __restrict__ deg,
                                                    int* __restrict__ total,
                                                    int* __restrict__ rowptr,
                                                    int* __restrict__ cursor) {
    const int i = blockIdx.x * 256 + threadIdx.x;
    const int lane = threadIdx.x & 63;
    int d = (i < NNODES) ? deg[i] : 0;
    int incl = d;
#pragma unroll
    for (int off = 1; off < 64; off <<= 1) {
        int t = __shfl_up(incl, off);
        if (lane >= off) incl += t;
    }
    int base = 0;
    if (lane == 63) base = atomicAdd(total, incl);   // incl@63 == wave total
    base = __shfl(base, 63);
    if (i < NNODES) {
        int pos = base + incl - d;                   // exclusive within wave
        rowptr[i] = pos;
        cursor[i] = pos;
    }
}

// fill with XCD-affine dst ranges: range r = blockIdx.x & 7 (round-robin
// block->XCD dispatch heuristic). All writes for a dst-range then come from
// ONE XCD, so its private L2 merges ~16 scattered 4B writes per 64B line
// before writeback (R12 counters: 1 write/line -> 52 MB HBM writes).
// Correctness does NOT depend on the mapping; worst case = no merging.
__global__ __launch_bounds__(256) void fill_kernel(const int* __restrict__ src,
                                                   const int* __restrict__ dst,
                                                   int* __restrict__ cursor,
                                                   int* __restrict__ csr_src) {
    const int r  = blockIdx.x & 7;          // dst-range (≈ XCD id)
    const int b  = blockIdx.x >> 3;         // sub-block within range group
    const int lo = r * NRANGE, hi = lo + NRANGE;
    for (int e = b * 256 + threadIdx.x; e < NEDGES; e += 32 * 256) {
        int d = dst[e];
        if (d >= lo && d < hi) {
            int pos = atomicAdd(&cursor[d], 1);
            csr_src[pos] = src[e];
        }
    }
}

// ---------------- GEMMs: LDS-tiled, register-blocked fp32 -----------------

// gemm1: h(N,128) = feat(N,128) @ W1(128,128), fused el/er.
// h stored as uint[N][64]: word j holds cols {2j, 2j+1} (bf16x2).
__global__ __launch_bounds__(256) void gemm1_kernel(
    const float* __restrict__ feat, const float* __restrict__ W,
    const float* __restrict__ al, const float* __restrict__ ar,
    unsigned* __restrict__ h, float* __restrict__ el, float* __restrict__ er) {
    __shared__ float As[64][36];      // pad 36: A-reads 2-way (free)
    __shared__ float Ws[32 * 128];
    const int tid = threadIdx.x;
    const int tx  = tid & 15;
    const int ty  = tid >> 4;
    const int n0  = blockIdx.x * 64;

    float acc[4][8];
#pragma unroll
    for (int i = 0; i < 4; ++i)
#pragma unroll
        for (int j = 0; j < 8; ++j) acc[i][j] = 0.f;

    for (int k0 = 0; k0 < 128; k0 += 32) {
#pragma unroll
        for (int i = 0; i < 2; ++i) {
            int fid = i * 256 + tid;
            int n = fid >> 3, j = fid & 7;
            float4 v = make_float4(0.f, 0.f, 0.f, 0.f);
            if (n0 + n < NNODES)
                v = *(const float4*)&feat[(size_t)(n0 + n) * 128 + k0 + 4 * j];
            *(float4*)&As[n][4 * j] = v;
        }
#pragma unroll
        for (int i = 0; i < 4; ++i) {
            int fid = i * 256 + tid;
            *(float4*)&Ws[fid * 4] = *(const float4*)&W[k0 * 128 + fid * 4];
        }
        __syncthreads();
#pragma unroll
        for (int k = 0; k < 32; ++k) {
            float a0 = As[ty * 4 + 0][k];
            float a1 = As[ty * 4 + 1][k];
            float a2 = As[ty * 4 + 2][k];
            float a3 = As[ty * 4 + 3][k];
            float4 w0 = *(const float4*)&Ws[k * 128 + tx * 4];
            float4 w1 = *(const float4*)&Ws[k * 128 + 64 + tx * 4];
            float wv[8] = {w0.x, w0.y, w0.z, w0.w, w1.x, w1.y, w1.z, w1.w};
#pragma unroll
            for (int j = 0; j < 8; ++j) {
                acc[0][j] = fmaf(a0, wv[j], acc[0][j]);
                acc[1][j] = fmaf(a1, wv[j], acc[1][j]);
                acc[2][j] = fmaf(a2, wv[j], acc[2][j]);
                acc[3][j] = fmaf(a3, wv[j], acc[3][j]);
            }
        }
        __syncthreads();
    }

    float alv[8], arv[8];
#pragma unroll
    for (int j = 0; j < 4; ++j) {
        alv[j]     = al[tx * 4 + j];        arv[j]     = ar[tx * 4 + j];
        alv[4 + j] = al[64 + tx * 4 + j];   arv[4 + j] = ar[64 + tx * 4 + j];
    }

#pragma unroll
    for (int i = 0; i < 4; ++i) {
        const int node = n0 + ty * 4 + i;
        if (node < NNODES) {
            uint2 o0 = {bfpack(acc[i][0], acc[i][1]), bfpack(acc[i][2], acc[i][3])};
            uint2 o1 = {bfpack(acc[i][4], acc[i][5]), bfpack(acc[i][6], acc[i][7])};
            *(uint2*)&h[(size_t)node * 64 + tx * 2]      = o0;
            *(uint2*)&h[(size_t)node * 64 + 32 + tx * 2] = o1;
        }
        float vl0 = 0.f, vr0 = 0.f, vl1 = 0.f, vr1 = 0.f;
#pragma unroll
        for (int j = 0; j < 4; ++j) {
            vl0 = fmaf(acc[i][j], alv[j], vl0);
            vr0 = fmaf(acc[i][j], arv[j], vr0);
            vl1 = fmaf(acc[i][4 + j], alv[4 + j], vl1);
            vr1 = fmaf(acc[i][4 + j], arv[4 + j], vr1);
        }
#pragma unroll
        for (int m = 1; m <= 8; m <<= 1) {
            vl0 += __shfl_xor(vl0, m); vr0 += __shfl_xor(vr0, m);
            vl1 += __shfl_xor(vl1, m); vr1 += __shfl_xor(vr1, m);
        }
        if (tx == 0 && node < NNODES) {
            el[node * 2 + 0] = vl0;  er[node * 2 + 0] = vr0;
            el[node * 2 + 1] = vl1;  er[node * 2 + 1] = vr1;
        }
    }
}

// gemm2: h2(N,64) = h1(N,128) @ W2(128,64), fused el2/er2 (H=1).
// h2 stored as uint[N][32]: word j holds cols {2j, 2j+1}.
__global__ __launch_bounds__(256) void gemm2_kernel(
    const float* __restrict__ h1, const float* __restrict__ W,
    const float* __restrict__ al, const float* __restrict__ ar,
    unsigned* __restrict__ h2, float* __restrict__ el, float* __restrict__ er) {
    __shared__ float As[128][34];
    __shared__ float Ws[32 * 64];
    const int tid = threadIdx.x;
    const int tx  = tid & 15;
    const int ty  = tid >> 4;
    const int n0  = blockIdx.x * 128;

    float acc[8][4];
#pragma unroll
    for (int i = 0; i < 8; ++i)
#pragma unroll
        for (int j = 0; j < 4; ++j) acc[i][j] = 0.f;

    for (int k0 = 0; k0 < 128; k0 += 32) {
#pragma unroll
        for (int i = 0; i < 4; ++i) {
            int fid = i * 256 + tid;
            int n = fid >> 3, j = fid & 7;
            float4 v = make_float4(0.f, 0.f, 0.f, 0.f);
            if (n0 + n < NNODES)
                v = *(const float4*)&h1[(size_t)(n0 + n) * 128 + k0 + 4 * j];
            *(float2*)&As[n][4 * j]     = make_float2(v.x, v.y);
            *(float2*)&As[n][4 * j + 2] = make_float2(v.z, v.w);
        }
#pragma unroll
        for (int i = 0; i < 2; ++i) {
            int fid = i * 256 + tid;
            *(float4*)&Ws[fid * 4] = *(const float4*)&W[k0 * 64 + fid * 4];
        }
        __syncthreads();
#pragma unroll
        for (int k = 0; k < 32; ++k) {
            float4 w = *(const float4*)&Ws[k * 64 + tx * 4];
            float wv[4] = {w.x, w.y, w.z, w.w};
#pragma unroll
            for (int i = 0; i < 8; ++i) {
                float a = As[ty * 8 + i][k];
#pragma unroll
                for (int j = 0; j < 4; ++j)
                    acc[i][j] = fmaf(a, wv[j], acc[i][j]);
            }
        }
        __syncthreads();
    }

    float alv[4], arv[4];
#pragma unroll
    for (int j = 0; j < 4; ++j) { alv[j] = al[tx * 4 + j]; arv[j] = ar[tx * 4 + j]; }

#pragma unroll
    for (int i = 0; i < 8; ++i) {
        const int node = n0 + ty * 8 + i;
        if (node < NNODES) {
            uint2 o = {bfpack(acc[i][0], acc[i][1]), bfpack(acc[i][2], acc[i][3])};
            *(uint2*)&h2[(size_t)node * 32 + tx * 2] = o;
        }
        float vl = 0.f, vr = 0.f;
#pragma unroll
        for (int j = 0; j < 4; ++j) {
            vl = fmaf(acc[i][j], alv[j], vl);
            vr = fmaf(acc[i][j], arv[j], vr);
        }
#pragma unroll
        for (int m = 1; m <= 8; m <<= 1) {
            vl += __shfl_xor(vl, m); vr += __shfl_xor(vr, m);
        }
        if (tx == 0 && node < NNODES) { el[node] = vl; er[node] = vr; }
    }
}

// ---- layer-1 aggregate: ONE wave per node, FOUR edges per gather iter -----
// Softmax phase identical to R8/R11 (64-lane, proven). Gather: quarter
// q=lane>>4 takes edge i+q; lane ql=lane&15 loads uint4 = cols 8ql..8ql+7
// (16 lanes x 16B = 256B row). Combine: shfl_xor 16 then 32.
__global__ __launch_bounds__(256) void aggregate1_kernel(
    const int* __restrict__ rowptr, const int* __restrict__ degv,
    const int* __restrict__ csr_src,
    const float* __restrict__ el, const float* __restrict__ er,
    const unsigned* __restrict__ hh, const float* __restrict__ bias,
    float* __restrict__ outp) {
    const int node = (blockIdx.x * 256 + threadIdx.x) >> 6;
    const int lane = threadIdx.x & 63;
    if (node >= NNODES) return;
    const int row = rowptr[node];
    const int deg = degv[node];
    const float er0 = er[node * 2 + 0];
    const float er1 = er[node * 2 + 1];

    // ---- edge scores + softmax stats (64-lane, proven structure) ----
    int   s_reg = 0;
    float v0 = -1e30f, v1 = -1e30f;
    if (lane < deg) {
        s_reg = csr_src[row + lane];
        float2 e = *(const float2*)&el[s_reg * 2];
        float a = e.x + er0; v0 = a > 0.f ? a : 0.2f * a;
        float b = e.y + er1; v1 = b > 0.f ? b : 0.2f * b;
    }
    float m0 = v0, m1 = v1;
    for (int i = 64 + lane; i < deg; i += 64) {          // rare (deg>64)
        int s = csr_src[row + i];
        float2 e = *(const float2*)&el[s * 2];
        float a = e.x + er0; a = a > 0.f ? a : 0.2f * a;
        float b = e.y + er1; b = b > 0.f ? b : 0.2f * b;
        m0 = fmaxf(m0, a); m1 = fmaxf(m1, b);
    }
#pragma unroll
    for (int off = 32; off > 0; off >>= 1) {
        m0 = fmaxf(m0, __shfl_xor(m0, off));
        m1 = fmaxf(m1, __shfl_xor(m1, off));
    }

    float p0 = (lane < deg) ? __expf(v0 - m0) : 0.f;
    float p1 = (lane < deg) ? __expf(v1 - m1) : 0.f;
    float ssum0 = p0, ssum1 = p1;
    for (int i = 64 + lane; i < deg; i += 64) {
        int s = csr_src[row + i];
        float2 e = *(const float2*)&el[s * 2];
        float a = e.x + er0; a = a > 0.f ? a : 0.2f * a;
        float b = e.y + er1; b = b > 0.f ? b : 0.2f * b;
        ssum0 += __expf(a - m0); ssum1 += __expf(b - m1);
    }
#pragma unroll
    for (int off = 32; off > 0; off >>= 1) {
        ssum0 += __shfl_xor(ssum0, off);
        ssum1 += __shfl_xor(ssum1, off);
    }

    // ---- gather: four edges per iteration (one per quarter-wave) ----
    const int  q     = lane >> 4;             // quarter: edge i+q
    const int  ql    = lane & 15;             // col group: 8ql..8ql+7
    const bool h1sel = (ql >= 8);             // cols 64.. are head1
    float a0r = 0.f, a1r = 0.f, a2r = 0.f, a3r = 0.f;
    float a4r = 0.f, a5r = 0.f, a6r = 0.f, a7r = 0.f;
    const int dmax = deg < 64 ? deg : 64;
    for (int i = 0; i < dmax; i += 4) {
        int eidx = i + q;
        int esafe = eidx & 63;                // mask for shuffle safety
        int   s  = __shfl(s_reg, esafe);
        float p0s = __shfl(p0, esafe);
        float p1s = __shfl(p1, esafe);
        if (eidx < dmax) {
            float alpha = h1sel ? p1s : p0s;
            uint4 hv = *(const uint4*)&hh[(size_t)s * 64 + 4 * ql];
            a0r = fmaf(alpha, bflo(hv.x), a0r);
            a1r = fmaf(alpha, bfhi(hv.x), a1r);
            a2r = fmaf(alpha, bflo(hv.y), a2r);
            a3r = fmaf(alpha, bfhi(hv.y), a3r);
            a4r = fmaf(alpha, bflo(hv.z), a4r);
            a5r = fmaf(alpha, bfhi(hv.z), a5r);
            a6r = fmaf(alpha, bflo(hv.w), a6r);
            a7r = fmaf(alpha, bfhi(hv.w), a7r);
        }
    }
    for (int i = 64; i < deg; i += 4) {       // rare tail (deg>64)
        int eidx = i + q;
        if (eidx < deg) {
            int s = csr_src[row + eidx];
            float2 e = *(const float2*)&el[s * 2];
            float a = e.x + er0; a = a > 0.f ? a : 0.2f * a;
            float b = e.y + er1; b = b > 0.f ? b : 0.2f * b;
            float alpha = h1sel ? __expf(b - m1) : __expf(a - m0);
            uint4 hv = *(const uint4*)&hh[(size_t)s * 64 + 4 * ql];
            a0r = fmaf(alpha, bflo(hv.x), a0r);
            a1r = fmaf(alpha, bfhi(hv.x), a1r);
            a2r = fmaf(alpha, bflo(hv.y), a2r);
            a3r = fmaf(alpha, bfhi(hv.y), a3r);
            a4r = fmaf(alpha, bflo(hv.z), a4r);
            a5r = fmaf(alpha, bfhi(hv.z), a5r);
            a6r = fmaf(alpha, bflo(hv.w), a6r);
            a7r = fmaf(alpha, bfhi(hv.w), a7r);
        }
    }
    // combine quarters (all four accumulated the same node's cols)
    a0r += __shfl_xor(a0r, 16);  a1r += __shfl_xor(a1r, 16);
    a2r += __shfl_xor(a2r, 16);  a3r += __shfl_xor(a3r, 16);
    a4r += __shfl_xor(a4r, 16);  a5r += __shfl_xor(a5r, 16);
    a6r += __shfl_xor(a6r, 16);  a7r += __shfl_xor(a7r, 16);
    a0r += __shfl_xor(a0r, 32);  a1r += __shfl_xor(a1r, 32);
    a2r += __shfl_xor(a2r, 32);  a3r += __shfl_xor(a3r, 32);
    a4r += __shfl_xor(a4r, 32);  a5r += __shfl_xor(a5r, 32);
    a6r += __shfl_xor(a6r, 32);  a7r += __shfl_xor(a7r, 32);

    if (lane < 16) {
        float ssum = h1sel ? ssum1 : ssum0;
        if (deg > 0) {
            float inv = 1.f / ssum;
            a0r *= inv; a1r *= inv; a2r *= inv; a3r *= inv;
            a4r *= inv; a5r *= inv; a6r *= inv; a7r *= inv;
        }
        float4 b0 = *(const float4*)&bias[8 * ql];
        float4 b1 = *(const float4*)&bias[8 * ql + 4];
        float o0 = a0r + b0.x, o1 = a1r + b0.y, o2 = a2r + b0.z, o3 = a3r + b0.w;
        float o4 = a4r + b1.x, o5 = a5r + b1.y, o6 = a6r + b1.z, o7 = a7r + b1.w;
        o0 = o0 > 0.f ? o0 : (__expf(o0) - 1.f);
        o1 = o1 > 0.f ? o1 : (__expf(o1) - 1.f);
        o2 = o2 > 0.f ? o2 : (__expf(o2) - 1.f);
        o3 = o3 > 0.f ? o3 : (__expf(o3) - 1.f);
        o4 = o4 > 0.f ? o4 : (__expf(o4) - 1.f);
        o5 = o5 > 0.f ? o5 : (__expf(o5) - 1.f);
        o6 = o6 > 0.f ? o6 : (__expf(o6) - 1.f);
        o7 = o7 > 0.f ? o7 : (__expf(o7) - 1.f);
        *(float4*)&outp[(size_t)node * 128 + 8 * ql]     = make_float4(o0, o1, o2, o3);
        *(float4*)&outp[(size_t)node * 128 + 8 * ql + 4] = make_float4(o4, o5, o6, o7);
    }
}

// ---- layer-2 aggregate: TWO nodes per wave, TWO edges per iter per node ---
// Halves = nodes (proven R8). Within a half: sub-half s2=(hl>>4) takes edge
// i+s2; lane sl=hl&15 loads uint2 = cols 4sl..4sl+3 (16 lanes x 8B = 128B).
// Combine: shfl_xor 16 (stays within the half).
__global__ __launch_bounds__(256) void aggregate2_kernel(
    const int* __restrict__ rowptr, const int* __restrict__ degv,
    const int* __restrict__ csr_src,
    const float* __restrict__ el, const float* __restrict__ er,
    const unsigned* __restrict__ hh, const float* __restrict__ bias,
    const float* __restrict__ h1, float* __restrict__ outp) {
    const int wid  = (blockIdx.x * 256 + threadIdx.x) >> 6;
    const int lane = threadIdx.x & 63;
    const int hl   = lane & 31;
    const int node = wid * 2 + (lane >> 5);
    if (node >= NNODES) return;
    const int row = rowptr[node];
    const int deg = degv[node];
    const float erd = er[node];

    int   s_reg = 0;
    float v_reg = -1e30f;
    if (hl < deg) {
        s_reg = csr_src[row + hl];
        float v = el[s_reg] + erd;
        v_reg = v > 0.f ? v : 0.2f * v;
    }
    float m = v_reg;
    for (int i = 32 + hl; i < deg; i += 32) {
        int s = csr_src[row + i];
        float v = el[s] + erd;
        v = v > 0.f ? v : 0.2f * v;
        m = fmaxf(m, v);
    }
#pragma unroll
    for (int off = 16; off > 0; off >>= 1) m = fmaxf(m, __shfl_xor(m, off));

    float p_reg = (hl < deg) ? __expf(v_reg - m) : 0.f;
    float ssum = p_reg;
    for (int i = 32 + hl; i < deg; i += 32) {
        int s = csr_src[row + i];
        float v = el[s] + erd;
        v = v > 0.f ? v : 0.2f * v;
        ssum += __expf(v - m);
    }
#pragma unroll
    for (int off = 16; off > 0; off >>= 1) ssum += __shfl_xor(ssum, off);

    const int s2 = hl >> 4;                   // sub-half: edge i+s2
    const int sl = hl & 15;                   // col group: 4sl..4sl+3
    float ax = 0.f, ay = 0.f, az = 0.f, aw = 0.f;
    const int dmax = deg < 32 ? deg : 32;
    int dmW = dmax;
    dmW = max(dmW, __shfl_xor(dmW, 32));      // uniform wave loop bound
    for (int i = 0; i < dmW; i += 2) {
        int eidx = i + s2;
        int esafe = (lane & 32) + (eidx & 31);     // own half's edge
        int   s = __shfl(s_reg, esafe);
        float p = __shfl(p_reg, esafe);
        if (eidx < dmax) {
            uint2 hv = *(const uint2*)&hh[(size_t)s * 32 + 2 * sl];
            ax = fmaf(p, bflo(hv.x), ax);
            ay = fmaf(p, bfhi(hv.x), ay);
            az = fmaf(p, bflo(hv.y), az);
            aw = fmaf(p, bfhi(hv.y), aw);
        }
    }
    for (int i = 32; i < deg; i += 2) {       // rare per-half tail (deg>32)
        int eidx = i + s2;
        if (eidx < deg) {
            int s = csr_src[row + eidx];
            float v = el[s] + erd;
            v = v > 0.f ? v : 0.2f * v;
            float p = __expf(v - m);
            uint2 hv = *(const uint2*)&hh[(size_t)s * 32 + 2 * sl];
            ax = fmaf(p, bflo(hv.x), ax);
            ay = fmaf(p, bfhi(hv.x), ay);
            az = fmaf(p, bflo(hv.y), az);
            aw = fmaf(p, bfhi(hv.y), aw);
        }
    }
    // combine sub-halves (xor 16 stays inside this node's half)
    ax += __shfl_xor(ax, 16);  ay += __shfl_xor(ay, 16);
    az += __shfl_xor(az, 16);  aw += __shfl_xor(aw, 16);

    if (sl == hl) {                           // lanes with s2==0 write
        if (deg > 0) {
            float inv = 1.f / ssum;
            ax *= inv; ay *= inv; az *= inv; aw *= inv;
        }
        float4 hA = *(const float4*)&h1[(size_t)node * 128 + 4 * sl];
        float4 hB = *(const float4*)&h1[(size_t)node * 128 + 64 + 4 * sl];
        float4 bb = *(const float4*)&bias[4 * sl];
        float o0 = ((hA.x + hB.x) * 0.5f + ax + bb.x) * 0.5f;
        float o1 = ((hA.y + hB.y) * 0.5f + ay + bb.y) * 0.5f;
        float o2 = ((hA.z + hB.z) * 0.5f + az + bb.z) * 0.5f;
        float o3 = ((hA.w + hB.w) * 0.5f + aw + bb.w) * 0.5f;
        *(float4*)&outp[(size_t)node * 64 + 4 * sl] = make_float4(o0, o1, o2, o3);
    }
}

// ---------------- launcher ----------------

extern "C" void kernel_launch(void* const* d_in, const int* in_sizes, int n_in,
                              void* d_out, int out_size, void* d_ws, size_t ws_size,
                              hipStream_t stream) {
    const float* feat = (const float*)d_in[0];
    const int*   src  = (const int*)d_in[1];
    const int*   dst  = (const int*)d_in[2];
    const float* W1   = (const float*)d_in[3];
    const float* al1  = (const float*)d_in[4];
    const float* ar1  = (const float*)d_in[5];
    const float* b1   = (const float*)d_in[6];
    const float* W2   = (const float*)d_in[7];
    const float* al2  = (const float*)d_in[8];
    const float* ar2  = (const float*)d_in[9];
    const float* b2   = (const float*)d_in[10];
    float* out = (float*)d_out;

    // workspace layout (4-byte units; ~50 MB total, 16B-aligned sections)
    int*      ideg  = (int*)d_ws;                        // N
    int*      itot  = ideg + NNODES;                     // 4 (global cursor)
    int*      irow  = itot + 4;                          // N
    int*      icur  = irow + NNODES;                     // N
    int*      icsr  = icur + NNODES;                     // E
    unsigned* fH1h  = (unsigned*)(icsr + NEDGES);        // N*64 uints (bf16x2)
    float*    fH1   = (float*)(fH1h + (size_t)NNODES * 64);  // N*128 fp32
    float*    fEl1  = fH1  + (size_t)NNODES * 128;       // N*2
    float*    fEr1  = fEl1 + (size_t)NNODES * 2;         // N*2
    unsigned* fH2h  = (unsigned*)(fEr1 + (size_t)NNODES * 2); // N*32 uints
    float*    fEl2  = (float*)(fH2h + (size_t)NNODES * 32);   // N
    float*    fEr2  = fEl2 + (size_t)NNODES;             // N

    // ---- CSR build: memset + hist + alloc + fill (4 dispatches) ----
    hipMemsetAsync(ideg, 0, (NNODES + 4) * sizeof(int), stream);  // deg + cursor
    hist_kernel<<<(NEDGES + 255) / 256, 256, 0, stream>>>(dst, ideg);
    alloc_kernel<<<(NNODES + 255) / 256, 256, 0, stream>>>(ideg, itot, irow, icur);
    fill_kernel<<<256, 256, 0, stream>>>(src, dst, icur, icsr);

    // ---- layer 1 ----
    gemm1_kernel<<<(NNODES + 63) / 64, 256, 0, stream>>>(feat, W1, al1, ar1,
                                                         fH1h, fEl1, fEr1);
    aggregate1_kernel<<<(NNODES + 3) / 4, 256, 0, stream>>>(
        irow, ideg, icsr, fEl1, fEr1, fH1h, b1, fH1);

    // ---- layer 2 ----
    gemm2_kernel<<<(NNODES + 127) / 128, 256, 0, stream>>>(fH1, W2, al2, ar2,
                                                           fH2h, fEl2, fEr2);
    aggregate2_kernel<<<(NNODES / 2 + 3) / 4, 256, 0, stream>>>(
        irow, ideg, icsr, fEl2, fEr2, fH2h, b2, fH1, out);
}

// Round 14
// 310.260 us; speedup vs baseline: 1.1625x; 1.1625x over previous
//
#include <hip/hip_runtime.h>
#include <math.h>

// Problem constants: N=50000, E=800000, IN=128, OUT=64, H1=2, H2=1
#define NNODES 50000
#define NEDGES 800000

// ---- manual bf16 pack/unpack (plain uint words) ----
__device__ __forceinline__ unsigned bfpack(float a, float b) {
    unsigned ua = __float_as_uint(a), ub = __float_as_uint(b);
    ua = (ua + 0x7fffu + ((ua >> 16) & 1u)) >> 16;
    ub = (ub + 0x7fffu + ((ub >> 16) & 1u)) >> 16;
    return ua | (ub << 16);
}
__device__ __forceinline__ float bflo(unsigned u) { return __uint_as_float(u << 16); }
__device__ __forceinline__ float bfhi(unsigned u) { return __uint_as_float(u & 0xffff0000u); }

// ---------------- CSR build (by dst; shared by both layers) ----------------
// csr_src stored as uint16 (src < 50000 < 65536): halves the scattered-write
// footprint (3.2 -> 1.6 MB region) and all CSR read traffic.

__global__ __launch_bounds__(256) void hist_kernel(const int* __restrict__ dst,
                                                   int* __restrict__ deg) {
    int e = blockIdx.x * 256 + threadIdx.x;
    if (e < NEDGES) atomicAdd(&deg[dst[e]], 1);
}

// row allocation WITHOUT global scan: wave-local shfl scan + 1 atomic/wave.
// Row order != node order (harmless: each row is still contiguous).
__global__ __launch_bounds__(256) void alloc_kernel(const int* __restrict__ deg,
                                                    int* __restrict__ total,
                                                    int* __restrict__ rowptr,
                                                    int* __restrict__ cursor) {
    const int i = blockIdx.x * 256 + threadIdx.x;
    const int lane = threadIdx.x & 63;
    int d = (i < NNODES) ? deg[i] : 0;
    int incl = d;
#pragma unroll
    for (int off = 1; off < 64; off <<= 1) {
        int t = __shfl_up(incl, off);
        if (lane >= off) incl += t;
    }
    int base = 0;
    if (lane == 63) base = atomicAdd(total, incl);   // incl@63 == wave total
    base = __shfl(base, 63);
    if (i < NNODES) {
        int pos = base + incl - d;                   // exclusive within wave
        rowptr[i] = pos;
        cursor[i] = pos;
    }
}

__global__ __launch_bounds__(256) void fill_kernel(
    const int* __restrict__ src, const int* __restrict__ dst,
    int* __restrict__ cursor, unsigned short* __restrict__ csr_src) {
    int e = blockIdx.x * 256 + threadIdx.x;
    if (e < NEDGES) {
        int pos = atomicAdd(&cursor[dst[e]], 1);
        csr_src[pos] = (unsigned short)src[e];
    }
}

// ---------------- GEMMs: LDS-tiled, register-blocked fp32 -----------------

// gemm1: h(N,128) = feat(N,128) @ W1(128,128), fused el/er.
// h stored as uint[N][64]: word j holds cols {2j, 2j+1} (bf16x2).
__global__ __launch_bounds__(256) void gemm1_kernel(
    const float* __restrict__ feat, const float* __restrict__ W,
    const float* __restrict__ al, const float* __restrict__ ar,
    unsigned* __restrict__ h, float* __restrict__ el, float* __restrict__ er) {
    __shared__ float As[64][36];      // pad 36: A-reads 2-way (free)
    __shared__ float Ws[32 * 128];
    const int tid = threadIdx.x;
    const int tx  = tid & 15;
    const int ty  = tid >> 4;
    const int n0  = blockIdx.x * 64;

    float acc[4][8];
#pragma unroll
    for (int i = 0; i < 4; ++i)
#pragma unroll
        for (int j = 0; j < 8; ++j) acc[i][j] = 0.f;

    for (int k0 = 0; k0 < 128; k0 += 32) {
#pragma unroll
        for (int i = 0; i < 2; ++i) {
            int fid = i * 256 + tid;
            int n = fid >> 3, j = fid & 7;
            float4 v = make_float4(0.f, 0.f, 0.f, 0.f);
            if (n0 + n < NNODES)
                v = *(const float4*)&feat[(size_t)(n0 + n) * 128 + k0 + 4 * j];
            *(float4*)&As[n][4 * j] = v;
        }
#pragma unroll
        for (int i = 0; i < 4; ++i) {
            int fid = i * 256 + tid;
            *(float4*)&Ws[fid * 4] = *(const float4*)&W[k0 * 128 + fid * 4];
        }
        __syncthreads();
#pragma unroll
        for (int k = 0; k < 32; ++k) {
            float a0 = As[ty * 4 + 0][k];
            float a1 = As[ty * 4 + 1][k];
            float a2 = As[ty * 4 + 2][k];
            float a3 = As[ty * 4 + 3][k];
            float4 w0 = *(const float4*)&Ws[k * 128 + tx * 4];
            float4 w1 = *(const float4*)&Ws[k * 128 + 64 + tx * 4];
            float wv[8] = {w0.x, w0.y, w0.z, w0.w, w1.x, w1.y, w1.z, w1.w};
#pragma unroll
            for (int j = 0; j < 8; ++j) {
                acc[0][j] = fmaf(a0, wv[j], acc[0][j]);
                acc[1][j] = fmaf(a1, wv[j], acc[1][j]);
                acc[2][j] = fmaf(a2, wv[j], acc[2][j]);
                acc[3][j] = fmaf(a3, wv[j], acc[3][j]);
            }
        }
        __syncthreads();
    }

    float alv[8], arv[8];
#pragma unroll
    for (int j = 0; j < 4; ++j) {
        alv[j]     = al[tx * 4 + j];        arv[j]     = ar[tx * 4 + j];
        alv[4 + j] = al[64 + tx * 4 + j];   arv[4 + j] = ar[64 + tx * 4 + j];
    }

#pragma unroll
    for (int i = 0; i < 4; ++i) {
        const int node = n0 + ty * 4 + i;
        if (node < NNODES) {
            uint2 o0 = {bfpack(acc[i][0], acc[i][1]), bfpack(acc[i][2], acc[i][3])};
            uint2 o1 = {bfpack(acc[i][4], acc[i][5]), bfpack(acc[i][6], acc[i][7])};
            *(uint2*)&h[(size_t)node * 64 + tx * 2]      = o0;
            *(uint2*)&h[(size_t)node * 64 + 32 + tx * 2] = o1;
        }
        float vl0 = 0.f, vr0 = 0.f, vl1 = 0.f, vr1 = 0.f;
#pragma unroll
        for (int j = 0; j < 4; ++j) {
            vl0 = fmaf(acc[i][j], alv[j], vl0);
            vr0 = fmaf(acc[i][j], arv[j], vr0);
            vl1 = fmaf(acc[i][4 + j], alv[4 + j], vl1);
            vr1 = fmaf(acc[i][4 + j], arv[4 + j], vr1);
        }
#pragma unroll
        for (int m = 1; m <= 8; m <<= 1) {
            vl0 += __shfl_xor(vl0, m); vr0 += __shfl_xor(vr0, m);
            vl1 += __shfl_xor(vl1, m); vr1 += __shfl_xor(vr1, m);
        }
        if (tx == 0 && node < NNODES) {
            el[node * 2 + 0] = vl0;  er[node * 2 + 0] = vr0;
            el[node * 2 + 1] = vl1;  er[node * 2 + 1] = vr1;
        }
    }
}

// gemm2: h2(N,64) = h1(N,128) @ W2(128,64), fused el2/er2 (H=1).
// h2 stored as uint[N][32]: word j holds cols {2j, 2j+1}.
__global__ __launch_bounds__(256) void gemm2_kernel(
    const float* __restrict__ h1, const float* __restrict__ W,
    const float* __restrict__ al, const float* __restrict__ ar,
    unsigned* __restrict__ h2, float* __restrict__ el, float* __restrict__ er) {
    __shared__ float As[128][34];
    __shared__ float Ws[32 * 64];
    const int tid = threadIdx.x;
    const int tx  = tid & 15;
    const int ty  = tid >> 4;
    const int n0  = blockIdx.x * 128;

    float acc[8][4];
#pragma unroll
    for (int i = 0; i < 8; ++i)
#pragma unroll
        for (int j = 0; j < 4; ++j) acc[i][j] = 0.f;

    for (int k0 = 0; k0 < 128; k0 += 32) {
#pragma unroll
        for (int i = 0; i < 4; ++i) {
            int fid = i * 256 + tid;
            int n = fid >> 3, j = fid & 7;
            float4 v = make_float4(0.f, 0.f, 0.f, 0.f);
            if (n0 + n < NNODES)
                v = *(const float4*)&h1[(size_t)(n0 + n) * 128 + k0 + 4 * j];
            *(float2*)&As[n][4 * j]     = make_float2(v.x, v.y);
            *(float2*)&As[n][4 * j + 2] = make_float2(v.z, v.w);
        }
#pragma unroll
        for (int i = 0; i < 2; ++i) {
            int fid = i * 256 + tid;
            *(float4*)&Ws[fid * 4] = *(const float4*)&W[k0 * 64 + fid * 4];
        }
        __syncthreads();
#pragma unroll
        for (int k = 0; k < 32; ++k) {
            float4 w = *(const float4*)&Ws[k * 64 + tx * 4];
            float wv[4] = {w.x, w.y, w.z, w.w};
#pragma unroll
            for (int i = 0; i < 8; ++i) {
                float a = As[ty * 8 + i][k];
#pragma unroll
                for (int j = 0; j < 4; ++j)
                    acc[i][j] = fmaf(a, wv[j], acc[i][j]);
            }
        }
        __syncthreads();
    }

    float alv[4], arv[4];
#pragma unroll
    for (int j = 0; j < 4; ++j) { alv[j] = al[tx * 4 + j]; arv[j] = ar[tx * 4 + j]; }

#pragma unroll
    for (int i = 0; i < 8; ++i) {
        const int node = n0 + ty * 8 + i;
        if (node < NNODES) {
            uint2 o = {bfpack(acc[i][0], acc[i][1]), bfpack(acc[i][2], acc[i][3])};
            *(uint2*)&h2[(size_t)node * 32 + tx * 2] = o;
        }
        float vl = 0.f, vr = 0.f;
#pragma unroll
        for (int j = 0; j < 4; ++j) {
            vl = fmaf(acc[i][j], alv[j], vl);
            vr = fmaf(acc[i][j], arv[j], vr);
        }
#pragma unroll
        for (int m = 1; m <= 8; m <<= 1) {
            vl += __shfl_xor(vl, m); vr += __shfl_xor(vr, m);
        }
        if (tx == 0 && node < NNODES) { el[node] = vl; er[node] = vr; }
    }
}

// ---- layer-1 aggregate: ONE wave per node, FOUR edges per gather iter -----
// Softmax phase identical to R8/R11 (64-lane, proven). Gather: quarter
// q=lane>>4 takes edge i+q; lane ql=lane&15 loads uint4 = cols 8ql..8ql+7
// (16 lanes x 16B = 256B row). Combine: shfl_xor 16 then 32.
__global__ __launch_bounds__(256) void aggregate1_kernel(
    const int* __restrict__ rowptr, const int* __restrict__ degv,
    const unsigned short* __restrict__ csr_src,
    const float* __restrict__ el, const float* __restrict__ er,
    const unsigned* __restrict__ hh, const float* __restrict__ bias,
    float* __restrict__ outp) {
    const int node = (blockIdx.x * 256 + threadIdx.x) >> 6;
    const int lane = threadIdx.x & 63;
    if (node >= NNODES) return;
    const int row = rowptr[node];
    const int deg = degv[node];
    const float er0 = er[node * 2 + 0];
    const float er1 = er[node * 2 + 1];

    // ---- edge scores + softmax stats (64-lane, proven structure) ----
    int   s_reg = 0;
    float v0 = -1e30f, v1 = -1e30f;
    if (lane < deg) {
        s_reg = (int)csr_src[row + lane];
        float2 e = *(const float2*)&el[s_reg * 2];
        float a = e.x + er0; v0 = a > 0.f ? a : 0.2f * a;
        float b = e.y + er1; v1 = b > 0.f ? b : 0.2f * b;
    }
    float m0 = v0, m1 = v1;
    for (int i = 64 + lane; i < deg; i += 64) {          // rare (deg>64)
        int s = (int)csr_src[row + i];
        float2 e = *(const float2*)&el[s * 2];
        float a = e.x + er0; a = a > 0.f ? a : 0.2f * a;
        float b = e.y + er1; b = b > 0.f ? b : 0.2f * b;
        m0 = fmaxf(m0, a); m1 = fmaxf(m1, b);
    }
#pragma unroll
    for (int off = 32; off > 0; off >>= 1) {
        m0 = fmaxf(m0, __shfl_xor(m0, off));
        m1 = fmaxf(m1, __shfl_xor(m1, off));
    }

    float p0 = (lane < deg) ? __expf(v0 - m0) : 0.f;
    float p1 = (lane < deg) ? __expf(v1 - m1) : 0.f;
    float ssum0 = p0, ssum1 = p1;
    for (int i = 64 + lane; i < deg; i += 64) {
        int s = (int)csr_src[row + i];
        float2 e = *(const float2*)&el[s * 2];
        float a = e.x + er0; a = a > 0.f ? a : 0.2f * a;
        float b = e.y + er1; b = b > 0.f ? b : 0.2f * b;
        ssum0 += __expf(a - m0); ssum1 += __expf(b - m1);
    }
#pragma unroll
    for (int off = 32; off > 0; off >>= 1) {
        ssum0 += __shfl_xor(ssum0, off);
        ssum1 += __shfl_xor(ssum1, off);
    }

    // ---- gather: four edges per iteration (one per quarter-wave) ----
    const int  q     = lane >> 4;             // quarter: edge i+q
    const int  ql    = lane & 15;             // col group: 8ql..8ql+7
    const bool h1sel = (ql >= 8);             // cols 64.. are head1
    float a0r = 0.f, a1r = 0.f, a2r = 0.f, a3r = 0.f;
    float a4r = 0.f, a5r = 0.f, a6r = 0.f, a7r = 0.f;
    const int dmax = deg < 64 ? deg : 64;
    for (int i = 0; i < dmax; i += 4) {
        int eidx = i + q;
        int esafe = eidx & 63;                // mask for shuffle safety
        int   s  = __shfl(s_reg, esafe);
        float p0s = __shfl(p0, esafe);
        float p1s = __shfl(p1, esafe);
        if (eidx < dmax) {
            float alpha = h1sel ? p1s : p0s;
            uint4 hv = *(const uint4*)&hh[(size_t)s * 64 + 4 * ql];
            a0r = fmaf(alpha, bflo(hv.x), a0r);
            a1r = fmaf(alpha, bfhi(hv.x), a1r);
            a2r = fmaf(alpha, bflo(hv.y), a2r);
            a3r = fmaf(alpha, bfhi(hv.y), a3r);
            a4r = fmaf(alpha, bflo(hv.z), a4r);
            a5r = fmaf(alpha, bfhi(hv.z), a5r);
            a6r = fmaf(alpha, bflo(hv.w), a6r);
            a7r = fmaf(alpha, bfhi(hv.w), a7r);
        }
    }
    for (int i = 64; i < deg; i += 4) {       // rare tail (deg>64)
        int eidx = i + q;
        if (eidx < deg) {
            int s = (int)csr_src[row + eidx];
            float2 e = *(const float2*)&el[s * 2];
            float a = e.x + er0; a = a > 0.f ? a : 0.2f * a;
            float b = e.y + er1; b = b > 0.f ? b : 0.2f * b;
            float alpha = h1sel ? __expf(b - m1) : __expf(a - m0);
            uint4 hv = *(const uint4*)&hh[(size_t)s * 64 + 4 * ql];
            a0r = fmaf(alpha, bflo(hv.x), a0r);
            a1r = fmaf(alpha, bfhi(hv.x), a1r);
            a2r = fmaf(alpha, bflo(hv.y), a2r);
            a3r = fmaf(alpha, bfhi(hv.y), a3r);
            a4r = fmaf(alpha, bflo(hv.z), a4r);
            a5r = fmaf(alpha, bfhi(hv.z), a5r);
            a6r = fmaf(alpha, bflo(hv.w), a6r);
            a7r = fmaf(alpha, bfhi(hv.w), a7r);
        }
    }
    // combine quarters (all four accumulated the same node's cols)
    a0r += __shfl_xor(a0r, 16);  a1r += __shfl_xor(a1r, 16);
    a2r += __shfl_xor(a2r, 16);  a3r += __shfl_xor(a3r, 16);
    a4r += __shfl_xor(a4r, 16);  a5r += __shfl_xor(a5r, 16);
    a6r += __shfl_xor(a6r, 16);  a7r += __shfl_xor(a7r, 16);
    a0r += __shfl_xor(a0r, 32);  a1r += __shfl_xor(a1r, 32);
    a2r += __shfl_xor(a2r, 32);  a3r += __shfl_xor(a3r, 32);
    a4r += __shfl_xor(a4r, 32);  a5r += __shfl_xor(a5r, 32);
    a6r += __shfl_xor(a6r, 32);  a7r += __shfl_xor(a7r, 32);

    if (lane < 16) {
        float ssum = h1sel ? ssum1 : ssum0;
        if (deg > 0) {
            float inv = 1.f / ssum;
            a0r *= inv; a1r *= inv; a2r *= inv; a3r *= inv;
            a4r *= inv; a5r *= inv; a6r *= inv; a7r *= inv;
        }
        float4 b0 = *(const float4*)&bias[8 * ql];
        float4 b1 = *(const float4*)&bias[8 * ql + 4];
        float o0 = a0r + b0.x, o1 = a1r + b0.y, o2 = a2r + b0.z, o3 = a3r + b0.w;
        float o4 = a4r + b1.x, o5 = a5r + b1.y, o6 = a6r + b1.z, o7 = a7r + b1.w;
        o0 = o0 > 0.f ? o0 : (__expf(o0) - 1.f);
        o1 = o1 > 0.f ? o1 : (__expf(o1) - 1.f);
        o2 = o2 > 0.f ? o2 : (__expf(o2) - 1.f);
        o3 = o3 > 0.f ? o3 : (__expf(o3) - 1.f);
        o4 = o4 > 0.f ? o4 : (__expf(o4) - 1.f);
        o5 = o5 > 0.f ? o5 : (__expf(o5) - 1.f);
        o6 = o6 > 0.f ? o6 : (__expf(o6) - 1.f);
        o7 = o7 > 0.f ? o7 : (__expf(o7) - 1.f);
        *(float4*)&outp[(size_t)node * 128 + 8 * ql]     = make_float4(o0, o1, o2, o3);
        *(float4*)&outp[(size_t)node * 128 + 8 * ql + 4] = make_float4(o4, o5, o6, o7);
    }
}

// ---- layer-2 aggregate: TWO nodes per wave, TWO edges per iter per node ---
// Halves = nodes (proven R8). Within a half: sub-half s2=(hl>>4) takes edge
// i+s2; lane sl=hl&15 loads uint2 = cols 4sl..4sl+3 (16 lanes x 8B = 128B).
// Combine: shfl_xor 16 (stays within the half).
__global__ __launch_bounds__(256) void aggregate2_kernel(
    const int* __restrict__ rowptr, const int* __restrict__ degv,
    const unsigned short* __restrict__ csr_src,
    const float* __restrict__ el, const float* __restrict__ er,
    const unsigned* __restrict__ hh, const float* __restrict__ bias,
    const float* __restrict__ h1, float* __restrict__ outp) {
    const int wid  = (blockIdx.x * 256 + threadIdx.x) >> 6;
    const int lane = threadIdx.x & 63;
    const int hl   = lane & 31;
    const int node = wid * 2 + (lane >> 5);
    if (node >= NNODES) return;
    const int row = rowptr[node];
    const int deg = degv[node];
    const float erd = er[node];

    int   s_reg = 0;
    float v_reg = -1e30f;
    if (hl < deg) {
        s_reg = (int)csr_src[row + hl];
        float v = el[s_reg] + erd;
        v_reg = v > 0.f ? v : 0.2f * v;
    }
    float m = v_reg;
    for (int i = 32 + hl; i < deg; i += 32) {
        int s = (int)csr_src[row + i];
        float v = el[s] + erd;
        v = v > 0.f ? v : 0.2f * v;
        m = fmaxf(m, v);
    }
#pragma unroll
    for (int off = 16; off > 0; off >>= 1) m = fmaxf(m, __shfl_xor(m, off));

    float p_reg = (hl < deg) ? __expf(v_reg - m) : 0.f;
    float ssum = p_reg;
    for (int i = 32 + hl; i < deg; i += 32) {
        int s = (int)csr_src[row + i];
        float v = el[s] + erd;
        v = v > 0.f ? v : 0.2f * v;
        ssum += __expf(v - m);
    }
#pragma unroll
    for (int off = 16; off > 0; off >>= 1) ssum += __shfl_xor(ssum, off);

    const int s2 = hl >> 4;                   // sub-half: edge i+s2
    const int sl = hl & 15;                   // col group: 4sl..4sl+3
    float ax = 0.f, ay = 0.f, az = 0.f, aw = 0.f;
    const int dmax = deg < 32 ? deg : 32;
    int dmW = dmax;
    dmW = max(dmW, __shfl_xor(dmW, 32));      // uniform wave loop bound
    for (int i = 0; i < dmW; i += 2) {
        int eidx = i + s2;
        int esafe = (lane & 32) + (eidx & 31);     // own half's edge
        int   s = __shfl(s_reg, esafe);
        float p = __shfl(p_reg, esafe);
        if (eidx < dmax) {
            uint2 hv = *(const uint2*)&hh[(size_t)s * 32 + 2 * sl];
            ax = fmaf(p, bflo(hv.x), ax);
            ay = fmaf(p, bfhi(hv.x), ay);
            az = fmaf(p, bflo(hv.y), az);
            aw = fmaf(p, bfhi(hv.y), aw);
        }
    }
    for (int i = 32; i < deg; i += 2) {       // rare per-half tail (deg>32)
        int eidx = i + s2;
        if (eidx < deg) {
            int s = (int)csr_src[row + eidx];
            float v = el[s] + erd;
            v = v > 0.f ? v : 0.2f * v;
            float p = __expf(v - m);
            uint2 hv = *(const uint2*)&hh[(size_t)s * 32 + 2 * sl];
            ax = fmaf(p, bflo(hv.x), ax);
            ay = fmaf(p, bfhi(hv.x), ay);
            az = fmaf(p, bflo(hv.y), az);
            aw = fmaf(p, bfhi(hv.y), aw);
        }
    }
    // combine sub-halves (xor 16 stays inside this node's half)
    ax += __shfl_xor(ax, 16);  ay += __shfl_xor(ay, 16);
    az += __shfl_xor(az, 16);  aw += __shfl_xor(aw, 16);

    if (sl == hl) {                           // lanes with s2==0 write
        if (deg > 0) {
            float inv = 1.f / ssum;
            ax *= inv; ay *= inv; az *= inv; aw *= inv;
        }
        float4 hA = *(const float4*)&h1[(size_t)node * 128 + 4 * sl];
        float4 hB = *(const float4*)&h1[(size_t)node * 128 + 64 + 4 * sl];
        float4 bb = *(const float4*)&bias[4 * sl];
        float o0 = ((hA.x + hB.x) * 0.5f + ax + bb.x) * 0.5f;
        float o1 = ((hA.y + hB.y) * 0.5f + ay + bb.y) * 0.5f;
        float o2 = ((hA.z + hB.z) * 0.5f + az + bb.z) * 0.5f;
        float o3 = ((hA.w + hB.w) * 0.5f + aw + bb.w) * 0.5f;
        *(float4*)&outp[(size_t)node * 64 + 4 * sl] = make_float4(o0, o1, o2, o3);
    }
}

// ---------------- launcher ----------------

extern "C" void kernel_launch(void* const* d_in, const int* in_sizes, int n_in,
                              void* d_out, int out_size, void* d_ws, size_t ws_size,
                              hipStream_t stream) {
    const float* feat = (const float*)d_in[0];
    const int*   src  = (const int*)d_in[1];
    const int*   dst  = (const int*)d_in[2];
    const float* W1   = (const float*)d_in[3];
    const float* al1  = (const float*)d_in[4];
    const float* ar1  = (const float*)d_in[5];
    const float* b1   = (const float*)d_in[6];
    const float* W2   = (const float*)d_in[7];
    const float* al2  = (const float*)d_in[8];
    const float* ar2  = (const float*)d_in[9];
    const float* b2   = (const float*)d_in[10];
    float* out = (float*)d_out;

    // workspace layout (4-byte units; ~48 MB total, 16B-aligned sections)
    int*            ideg   = (int*)d_ws;                     // N
    int*            itot   = ideg + NNODES;                  // 4 (global cursor)
    int*            irow   = itot + 4;                       // N
    int*            icur   = irow + NNODES;                  // N
    unsigned short* icsr16 = (unsigned short*)(icur + NNODES); // E ushorts = E/2 uints
    unsigned*       fH1h   = (unsigned*)(icur + NNODES + NEDGES / 2); // N*64 uints
    float*          fH1    = (float*)(fH1h + (size_t)NNODES * 64);    // N*128 fp32
    float*          fEl1   = fH1  + (size_t)NNODES * 128;    // N*2
    float*          fEr1   = fEl1 + (size_t)NNODES * 2;      // N*2
    unsigned*       fH2h   = (unsigned*)(fEr1 + (size_t)NNODES * 2);  // N*32 uints
    float*          fEl2   = (float*)(fH2h + (size_t)NNODES * 32);    // N
    float*          fEr2   = fEl2 + (size_t)NNODES;          // N

    // ---- CSR build: memset + hist + alloc + fill (4 dispatches) ----
    hipMemsetAsync(ideg, 0, (NNODES + 4) * sizeof(int), stream);  // deg + cursor
    hist_kernel<<<(NEDGES + 255) / 256, 256, 0, stream>>>(dst, ideg);
    alloc_kernel<<<(NNODES + 255) / 256, 256, 0, stream>>>(ideg, itot, irow, icur);
    fill_kernel<<<(NEDGES + 255) / 256, 256, 0, stream>>>(src, dst, icur, icsr16);

    // ---- layer 1 ----
    gemm1_kernel<<<(NNODES + 63) / 64, 256, 0, stream>>>(feat, W1, al1, ar1,
                                                         fH1h, fEl1, fEr1);
    aggregate1_kernel<<<(NNODES + 3) / 4, 256, 0, stream>>>(
        irow, ideg, icsr16, fEl1, fEr1, fH1h, b1, fH1);

    // ---- layer 2 ----
    gemm2_kernel<<<(NNODES + 127) / 128, 256, 0, stream>>>(fH1, W2, al2, ar2,
                                                           fH2h, fEl2, fEr2);
    aggregate2_kernel<<<(NNODES / 2 + 3) / 4, 256, 0, stream>>>(
        irow, ideg, icsr16, fEl2, fEr2, fH2h, b2, fH1, out);
}

// Round 15
// 296.329 us; speedup vs baseline: 1.2172x; 1.0470x over previous
//
#include <hip/hip_runtime.h>
#include <math.h>

// Problem constants: N=50000, E=800000, IN=128, OUT=64, H1=2, H2=1
#define NNODES 50000
#define NEDGES 800000

typedef short bf16x8 __attribute__((ext_vector_type(8)));
typedef float f32x4  __attribute__((ext_vector_type(4)));

// ---- manual bf16 pack/unpack (plain uint words) ----
__device__ __forceinline__ unsigned bfpack(float a, float b) {
    unsigned ua = __float_as_uint(a), ub = __float_as_uint(b);
    ua = (ua + 0x7fffu + ((ua >> 16) & 1u)) >> 16;
    ub = (ub + 0x7fffu + ((ub >> 16) & 1u)) >> 16;
    return ua | (ub << 16);
}
__device__ __forceinline__ float bflo(unsigned u) { return __uint_as_float(u << 16); }
__device__ __forceinline__ float bfhi(unsigned u) { return __uint_as_float(u & 0xffff0000u); }

// ---------------- CSR build (by dst; shared by both layers) ----------------

__global__ __launch_bounds__(256) void hist_kernel(const int* __restrict__ dst,
                                                   int* __restrict__ deg) {
    int e = blockIdx.x * 256 + threadIdx.x;
    if (e < NEDGES) atomicAdd(&deg[dst[e]], 1);
}

__global__ __launch_bounds__(256) void alloc_kernel(const int* __restrict__ deg,
                                                    int* __restrict__ total,
                                                    int* __restrict__ rowptr,
                                                    int* __restrict__ cursor) {
    const int i = blockIdx.x * 256 + threadIdx.x;
    const int lane = threadIdx.x & 63;
    int d = (i < NNODES) ? deg[i] : 0;
    int incl = d;
#pragma unroll
    for (int off = 1; off < 64; off <<= 1) {
        int t = __shfl_up(incl, off);
        if (lane >= off) incl += t;
    }
    int base = 0;
    if (lane == 63) base = atomicAdd(total, incl);
    base = __shfl(base, 63);
    if (i < NNODES) {
        int pos = base + incl - d;
        rowptr[i] = pos;
        cursor[i] = pos;
    }
}

__global__ __launch_bounds__(256) void fill_kernel(
    const int* __restrict__ src, const int* __restrict__ dst,
    int* __restrict__ cursor, unsigned short* __restrict__ csr_src) {
    int e = blockIdx.x * 256 + threadIdx.x;
    if (e < NEDGES) {
        int pos = atomicAdd(&cursor[dst[e]], 1);
        csr_src[pos] = (unsigned short)src[e];
    }
}

// ---------------- gemm1: MFMA bf16 ----------------
// prep: W1t packed bf16, [n][64 words]: word j = k-pair (2j,2j+1) of W[k][n]
__global__ __launch_bounds__(256) void w1t_kernel(const float* __restrict__ W,
                                                  unsigned* __restrict__ Wt) {
    int w = blockIdx.x * 256 + threadIdx.x;   // 8192 words
    int n = w >> 6, j = w & 63;
    Wt[w] = bfpack(W[(2 * j) * 128 + n], W[(2 * j + 1) * 128 + n]);
}

// h(N,128) = feat(N,128) @ W1(128,128) via mfma_f32_16x16x32_bf16.
// Block = 64 rows; 4 waves x 16 rows. Whole W^T + A-tile staged in LDS
// (bf16, row stride 68 words -> 2-way bank alias = free), ONE barrier,
// then 4 k-chunks x 8 n-tiles of MFMA. A-op: [m=lane&15][k=quad*8+j];
// B-op: [n=lane&15][k=quad*8+j] (= W^T rows); C/D: col=lane&15,
// row=quad*4+reg (m89/m91-verified).
__global__ __launch_bounds__(256) void gemm1_kernel(
    const float* __restrict__ feat, const unsigned* __restrict__ Wt,
    const float* __restrict__ al, const float* __restrict__ ar,
    unsigned* __restrict__ h, float* __restrict__ el, float* __restrict__ er) {
    __shared__ unsigned Wb[128 * 68];   // [n][68] (64 used + 4 pad)
    __shared__ unsigned Ab[64 * 68];    // [m][68]
    const int tid = threadIdx.x;
    const int n0  = blockIdx.x * 64;

    // stage W^T: 2048 uint4, coalesced
#pragma unroll
    for (int i = 0; i < 8; ++i) {
        int id = i * 256 + tid;               // uint4 id 0..2047
        int n = id >> 4, c = (id & 15) * 4;
        *(uint4*)&Wb[n * 68 + c] = *(const uint4*)&Wt[n * 64 + c];
    }
    // stage A: 2048 float4 -> bf16 uint2
#pragma unroll
    for (int i = 0; i < 8; ++i) {
        int f = i * 256 + tid;                // float4 id 0..2047
        int m = f >> 5, cf = (f & 31) * 4;    // row, col (floats)
        float4 v = make_float4(0.f, 0.f, 0.f, 0.f);
        if (n0 + m < NNODES)
            v = *(const float4*)&feat[(size_t)(n0 + m) * 128 + cf];
        uint2 p = {bfpack(v.x, v.y), bfpack(v.z, v.w)};
        *(uint2*)&Ab[m * 68 + cf / 2] = p;
    }
    __syncthreads();

    const int w  = tid >> 6;      // wave: rows 16w..16w+15
    const int l  = tid & 63;
    const int ml = l & 15;
    const int q  = l >> 4;
    f32x4 acc[8];
#pragma unroll
    for (int t = 0; t < 8; ++t) acc[t] = (f32x4){0.f, 0.f, 0.f, 0.f};

#pragma unroll
    for (int kc = 0; kc < 4; ++kc) {
        const int kw = kc * 16 + q * 4;       // word offset: k0/2 + quad*4
        uint4 a4 = *(uint4*)&Ab[(16 * w + ml) * 68 + kw];
        bf16x8 af = *(bf16x8*)&a4;
#pragma unroll
        for (int t = 0; t < 8; ++t) {
            uint4 b4 = *(uint4*)&Wb[(t * 16 + ml) * 68 + kw];
            bf16x8 bf = *(bf16x8*)&b4;
            acc[t] = __builtin_amdgcn_mfma_f32_16x16x32_bf16(af, bf, acc[t], 0, 0, 0);
        }
    }

    // attn vectors for this lane's col in each tile (al[t*16+ml] covers both heads)
    float av[8], rv[8];
#pragma unroll
    for (int t = 0; t < 8; ++t) { av[t] = al[t * 16 + ml]; rv[t] = ar[t * 16 + ml]; }

#pragma unroll
    for (int r = 0; r < 4; ++r) {
        const int node = n0 + 16 * w + q * 4 + r;
        float e0 = 0.f, e1 = 0.f, f0 = 0.f, f1 = 0.f;
#pragma unroll
        for (int t = 0; t < 8; ++t) {
            float v = acc[t][r];
            if (t < 4) { e0 = fmaf(v, av[t], e0); f0 = fmaf(v, rv[t], f0); }
            else       { e1 = fmaf(v, av[t], e1); f1 = fmaf(v, rv[t], f1); }
            float pv = __shfl_xor(v, 1);      // col c+1 (all lanes execute)
            if ((ml & 1) == 0 && node < NNODES)
                h[(size_t)node * 64 + t * 8 + (ml >> 1)] = bfpack(v, pv);
        }
#pragma unroll
        for (int mm = 1; mm <= 8; mm <<= 1) { // reduce over 16 cols (in-quad)
            e0 += __shfl_xor(e0, mm); e1 += __shfl_xor(e1, mm);
            f0 += __shfl_xor(f0, mm); f1 += __shfl_xor(f1, mm);
        }
        if (ml == 0 && node < NNODES) {
            el[node * 2 + 0] = e0; el[node * 2 + 1] = e1;
            er[node * 2 + 0] = f0; er[node * 2 + 1] = f1;
        }
    }
}

// gemm2: h2(N,64) = h1(N,128) @ W2(128,64), fused el2/er2 (H=1). fp32 VALU.
__global__ __launch_bounds__(256) void gemm2_kernel(
    const float* __restrict__ h1, const float* __restrict__ W,
    const float* __restrict__ al, const float* __restrict__ ar,
    unsigned* __restrict__ h2, float* __restrict__ el, float* __restrict__ er) {
    __shared__ float As[128][34];
    __shared__ float Ws[32 * 64];
    const int tid = threadIdx.x;
    const int tx  = tid & 15;
    const int ty  = tid >> 4;
    const int n0  = blockIdx.x * 128;

    float acc[8][4];
#pragma unroll
    for (int i = 0; i < 8; ++i)
#pragma unroll
        for (int j = 0; j < 4; ++j) acc[i][j] = 0.f;

    for (int k0 = 0; k0 < 128; k0 += 32) {
#pragma unroll
        for (int i = 0; i < 4; ++i) {
            int fid = i * 256 + tid;
            int n = fid >> 3, j = fid & 7;
            float4 v = make_float4(0.f, 0.f, 0.f, 0.f);
            if (n0 + n < NNODES)
                v = *(const float4*)&h1[(size_t)(n0 + n) * 128 + k0 + 4 * j];
            *(float2*)&As[n][4 * j]     = make_float2(v.x, v.y);
            *(float2*)&As[n][4 * j + 2] = make_float2(v.z, v.w);
        }
#pragma unroll
        for (int i = 0; i < 2; ++i) {
            int fid = i * 256 + tid;
            *(float4*)&Ws[fid * 4] = *(const float4*)&W[k0 * 64 + fid * 4];
        }
        __syncthreads();
#pragma unroll
        for (int k = 0; k < 32; ++k) {
            float4 w = *(const float4*)&Ws[k * 64 + tx * 4];
            float wv[4] = {w.x, w.y, w.z, w.w};
#pragma unroll
            for (int i = 0; i < 8; ++i) {
                float a = As[ty * 8 + i][k];
#pragma unroll
                for (int j = 0; j < 4; ++j)
                    acc[i][j] = fmaf(a, wv[j], acc[i][j]);
            }
        }
        __syncthreads();
    }

    float alv[4], arv[4];
#pragma unroll
    for (int j = 0; j < 4; ++j) { alv[j] = al[tx * 4 + j]; arv[j] = ar[tx * 4 + j]; }

#pragma unroll
    for (int i = 0; i < 8; ++i) {
        const int node = n0 + ty * 8 + i;
        if (node < NNODES) {
            uint2 o = {bfpack(acc[i][0], acc[i][1]), bfpack(acc[i][2], acc[i][3])};
            *(uint2*)&h2[(size_t)node * 32 + tx * 2] = o;
        }
        float vl = 0.f, vr = 0.f;
#pragma unroll
        for (int j = 0; j < 4; ++j) {
            vl = fmaf(acc[i][j], alv[j], vl);
            vr = fmaf(acc[i][j], arv[j], vr);
        }
#pragma unroll
        for (int m = 1; m <= 8; m <<= 1) {
            vl += __shfl_xor(vl, m); vr += __shfl_xor(vr, m);
        }
        if (tx == 0 && node < NNODES) { el[node] = vl; er[node] = vr; }
    }
}

// ---- layer-1 aggregate: ONE wave per node, FOUR edges per gather iter -----
__global__ __launch_bounds__(256) void aggregate1_kernel(
    const int* __restrict__ rowptr, const int* __restrict__ degv,
    const unsigned short* __restrict__ csr_src,
    const float* __restrict__ el, const float* __restrict__ er,
    const unsigned* __restrict__ hh, const float* __restrict__ bias,
    float* __restrict__ outp) {
    const int node = (blockIdx.x * 256 + threadIdx.x) >> 6;
    const int lane = threadIdx.x & 63;
    if (node >= NNODES) return;
    const int row = rowptr[node];
    const int deg = degv[node];
    const float er0 = er[node * 2 + 0];
    const float er1 = er[node * 2 + 1];

    int   s_reg = 0;
    float v0 = -1e30f, v1 = -1e30f;
    if (lane < deg) {
        s_reg = (int)csr_src[row + lane];
        float2 e = *(const float2*)&el[s_reg * 2];
        float a = e.x + er0; v0 = a > 0.f ? a : 0.2f * a;
        float b = e.y + er1; v1 = b > 0.f ? b : 0.2f * b;
    }
    float m0 = v0, m1 = v1;
    for (int i = 64 + lane; i < deg; i += 64) {
        int s = (int)csr_src[row + i];
        float2 e = *(const float2*)&el[s * 2];
        float a = e.x + er0; a = a > 0.f ? a : 0.2f * a;
        float b = e.y + er1; b = b > 0.f ? b : 0.2f * b;
        m0 = fmaxf(m0, a); m1 = fmaxf(m1, b);
    }
#pragma unroll
    for (int off = 32; off > 0; off >>= 1) {
        m0 = fmaxf(m0, __shfl_xor(m0, off));
        m1 = fmaxf(m1, __shfl_xor(m1, off));
    }

    float p0 = (lane < deg) ? __expf(v0 - m0) : 0.f;
    float p1 = (lane < deg) ? __expf(v1 - m1) : 0.f;
    float ssum0 = p0, ssum1 = p1;
    for (int i = 64 + lane; i < deg; i += 64) {
        int s = (int)csr_src[row + i];
        float2 e = *(const float2*)&el[s * 2];
        float a = e.x + er0; a = a > 0.f ? a : 0.2f * a;
        float b = e.y + er1; b = b > 0.f ? b : 0.2f * b;
        ssum0 += __expf(a - m0); ssum1 += __expf(b - m1);
    }
#pragma unroll
    for (int off = 32; off > 0; off >>= 1) {
        ssum0 += __shfl_xor(ssum0, off);
        ssum1 += __shfl_xor(ssum1, off);
    }

    const int  q     = lane >> 4;
    const int  ql    = lane & 15;
    const bool h1sel = (ql >= 8);
    float a0r = 0.f, a1r = 0.f, a2r = 0.f, a3r = 0.f;
    float a4r = 0.f, a5r = 0.f, a6r = 0.f, a7r = 0.f;
    const int dmax = deg < 64 ? deg : 64;
    for (int i = 0; i < dmax; i += 4) {
        int eidx = i + q;
        int esafe = eidx & 63;
        int   s  = __shfl(s_reg, esafe);
        float p0s = __shfl(p0, esafe);
        float p1s = __shfl(p1, esafe);
        if (eidx < dmax) {
            float alpha = h1sel ? p1s : p0s;
            uint4 hv = *(const uint4*)&hh[(size_t)s * 64 + 4 * ql];
            a0r = fmaf(alpha, bflo(hv.x), a0r);
            a1r = fmaf(alpha, bfhi(hv.x), a1r);
            a2r = fmaf(alpha, bflo(hv.y), a2r);
            a3r = fmaf(alpha, bfhi(hv.y), a3r);
            a4r = fmaf(alpha, bflo(hv.z), a4r);
            a5r = fmaf(alpha, bfhi(hv.z), a5r);
            a6r = fmaf(alpha, bflo(hv.w), a6r);
            a7r = fmaf(alpha, bfhi(hv.w), a7r);
        }
    }
    for (int i = 64; i < deg; i += 4) {
        int eidx = i + q;
        if (eidx < deg) {
            int s = (int)csr_src[row + eidx];
            float2 e = *(const float2*)&el[s * 2];
            float a = e.x + er0; a = a > 0.f ? a : 0.2f * a;
            float b = e.y + er1; b = b > 0.f ? b : 0.2f * b;
            float alpha = h1sel ? __expf(b - m1) : __expf(a - m0);
            uint4 hv = *(const uint4*)&hh[(size_t)s * 64 + 4 * ql];
            a0r = fmaf(alpha, bflo(hv.x), a0r);
            a1r = fmaf(alpha, bfhi(hv.x), a1r);
            a2r = fmaf(alpha, bflo(hv.y), a2r);
            a3r = fmaf(alpha, bfhi(hv.y), a3r);
            a4r = fmaf(alpha, bflo(hv.z), a4r);
            a5r = fmaf(alpha, bfhi(hv.z), a5r);
            a6r = fmaf(alpha, bflo(hv.w), a6r);
            a7r = fmaf(alpha, bfhi(hv.w), a7r);
        }
    }
    a0r += __shfl_xor(a0r, 16);  a1r += __shfl_xor(a1r, 16);
    a2r += __shfl_xor(a2r, 16);  a3r += __shfl_xor(a3r, 16);
    a4r += __shfl_xor(a4r, 16);  a5r += __shfl_xor(a5r, 16);
    a6r += __shfl_xor(a6r, 16);  a7r += __shfl_xor(a7r, 16);
    a0r += __shfl_xor(a0r, 32);  a1r += __shfl_xor(a1r, 32);
    a2r += __shfl_xor(a2r, 32);  a3r += __shfl_xor(a3r, 32);
    a4r += __shfl_xor(a4r, 32);  a5r += __shfl_xor(a5r, 32);
    a6r += __shfl_xor(a6r, 32);  a7r += __shfl_xor(a7r, 32);

    if (lane < 16) {
        float ssum = h1sel ? ssum1 : ssum0;
        if (deg > 0) {
            float inv = 1.f / ssum;
            a0r *= inv; a1r *= inv; a2r *= inv; a3r *= inv;
            a4r *= inv; a5r *= inv; a6r *= inv; a7r *= inv;
        }
        float4 b0 = *(const float4*)&bias[8 * ql];
        float4 b1 = *(const float4*)&bias[8 * ql + 4];
        float o0 = a0r + b0.x, o1 = a1r + b0.y, o2 = a2r + b0.z, o3 = a3r + b0.w;
        float o4 = a4r + b1.x, o5 = a5r + b1.y, o6 = a6r + b1.z, o7 = a7r + b1.w;
        o0 = o0 > 0.f ? o0 : (__expf(o0) - 1.f);
        o1 = o1 > 0.f ? o1 : (__expf(o1) - 1.f);
        o2 = o2 > 0.f ? o2 : (__expf(o2) - 1.f);
        o3 = o3 > 0.f ? o3 : (__expf(o3) - 1.f);
        o4 = o4 > 0.f ? o4 : (__expf(o4) - 1.f);
        o5 = o5 > 0.f ? o5 : (__expf(o5) - 1.f);
        o6 = o6 > 0.f ? o6 : (__expf(o6) - 1.f);
        o7 = o7 > 0.f ? o7 : (__expf(o7) - 1.f);
        *(float4*)&outp[(size_t)node * 128 + 8 * ql]     = make_float4(o0, o1, o2, o3);
        *(float4*)&outp[(size_t)node * 128 + 8 * ql + 4] = make_float4(o4, o5, o6, o7);
    }
}

// ---- layer-2 aggregate: TWO nodes per wave, TWO edges per iter per node ---
__global__ __launch_bounds__(256) void aggregate2_kernel(
    const int* __restrict__ rowptr, const int* __restrict__ degv,
    const unsigned short* __restrict__ csr_src,
    const float* __restrict__ el, const float* __restrict__ er,
    const unsigned* __restrict__ hh, const float* __restrict__ bias,
    const float* __restrict__ h1, float* __restrict__ outp) {
    const int wid  = (blockIdx.x * 256 + threadIdx.x) >> 6;
    const int lane = threadIdx.x & 63;
    const int hl   = lane & 31;
    const int node = wid * 2 + (lane >> 5);
    if (node >= NNODES) return;
    const int row = rowptr[node];
    const int deg = degv[node];
    const float erd = er[node];

    int   s_reg = 0;
    float v_reg = -1e30f;
    if (hl < deg) {
        s_reg = (int)csr_src[row + hl];
        float v = el[s_reg] + erd;
        v_reg = v > 0.f ? v : 0.2f * v;
    }
    float m = v_reg;
    for (int i = 32 + hl; i < deg; i += 32) {
        int s = (int)csr_src[row + i];
        float v = el[s] + erd;
        v = v > 0.f ? v : 0.2f * v;
        m = fmaxf(m, v);
    }
#pragma unroll
    for (int off = 16; off > 0; off >>= 1) m = fmaxf(m, __shfl_xor(m, off));

    float p_reg = (hl < deg) ? __expf(v_reg - m) : 0.f;
    float ssum = p_reg;
    for (int i = 32 + hl; i < deg; i += 32) {
        int s = (int)csr_src[row + i];
        float v = el[s] + erd;
        v = v > 0.f ? v : 0.2f * v;
        ssum += __expf(v - m);
    }
#pragma unroll
    for (int off = 16; off > 0; off >>= 1) ssum += __shfl_xor(ssum, off);

    const int s2 = hl >> 4;
    const int sl = hl & 15;
    float ax = 0.f, ay = 0.f, az = 0.f, aw = 0.f;
    const int dmax = deg < 32 ? deg : 32;
    int dmW = dmax;
    dmW = max(dmW, __shfl_xor(dmW, 32));
    for (int i = 0; i < dmW; i += 2) {
        int eidx = i + s2;
        int esafe = (lane & 32) + (eidx & 31);
        int   s = __shfl(s_reg, esafe);
        float p = __shfl(p_reg, esafe);
        if (eidx < dmax) {
            uint2 hv = *(const uint2*)&hh[(size_t)s * 32 + 2 * sl];
            ax = fmaf(p, bflo(hv.x), ax);
            ay = fmaf(p, bfhi(hv.x), ay);
            az = fmaf(p, bflo(hv.y), az);
            aw = fmaf(p, bfhi(hv.y), aw);
        }
    }
    for (int i = 32; i < deg; i += 2) {
        int eidx = i + s2;
        if (eidx < deg) {
            int s = (int)csr_src[row + eidx];
            float v = el[s] + erd;
            v = v > 0.f ? v : 0.2f * v;
            float p = __expf(v - m);
            uint2 hv = *(const uint2*)&hh[(size_t)s * 32 + 2 * sl];
            ax = fmaf(p, bflo(hv.x), ax);
            ay = fmaf(p, bfhi(hv.x), ay);
            az = fmaf(p, bflo(hv.y), az);
            aw = fmaf(p, bfhi(hv.y), aw);
        }
    }
    ax += __shfl_xor(ax, 16);  ay += __shfl_xor(ay, 16);
    az += __shfl_xor(az, 16);  aw += __shfl_xor(aw, 16);

    if (sl == hl) {
        if (deg > 0) {
            float inv = 1.f / ssum;
            ax *= inv; ay *= inv; az *= inv; aw *= inv;
        }
        float4 hA = *(const float4*)&h1[(size_t)node * 128 + 4 * sl];
        float4 hB = *(const float4*)&h1[(size_t)node * 128 + 64 + 4 * sl];
        float4 bb = *(const float4*)&bias[4 * sl];
        float o0 = ((hA.x + hB.x) * 0.5f + ax + bb.x) * 0.5f;
        float o1 = ((hA.y + hB.y) * 0.5f + ay + bb.y) * 0.5f;
        float o2 = ((hA.z + hB.z) * 0.5f + az + bb.z) * 0.5f;
        float o3 = ((hA.w + hB.w) * 0.5f + aw + bb.w) * 0.5f;
        *(float4*)&outp[(size_t)node * 64 + 4 * sl] = make_float4(o0, o1, o2, o3);
    }
}

// ---------------- launcher ----------------

extern "C" void kernel_launch(void* const* d_in, const int* in_sizes, int n_in,
                              void* d_out, int out_size, void* d_ws, size_t ws_size,
                              hipStream_t stream) {
    const float* feat = (const float*)d_in[0];
    const int*   src  = (const int*)d_in[1];
    const int*   dst  = (const int*)d_in[2];
    const float* W1   = (const float*)d_in[3];
    const float* al1  = (const float*)d_in[4];
    const float* ar1  = (const float*)d_in[5];
    const float* b1   = (const float*)d_in[6];
    const float* W2   = (const float*)d_in[7];
    const float* al2  = (const float*)d_in[8];
    const float* ar2  = (const float*)d_in[9];
    const float* b2   = (const float*)d_in[10];
    float* out = (float*)d_out;

    // workspace layout (4-byte units; ~48 MB total, 16B-aligned sections)
    int*            ideg   = (int*)d_ws;                     // N
    int*            itot   = ideg + NNODES;                  // 4
    int*            irow   = itot + 4;                       // N
    int*            icur   = irow + NNODES;                  // N
    unsigned*       iw1t   = (unsigned*)(icur + NNODES);     // 8192 (W1^T bf16)
    unsigned short* icsr16 = (unsigned short*)(iw1t + 8192); // E ushorts
    unsigned*       fH1h   = (unsigned*)(iw1t + 8192 + NEDGES / 2); // N*64 uints
    float*          fH1    = (float*)(fH1h + (size_t)NNODES * 64);  // N*128
    float*          fEl1   = fH1  + (size_t)NNODES * 128;    // N*2
    float*          fEr1   = fEl1 + (size_t)NNODES * 2;      // N*2
    unsigned*       fH2h   = (unsigned*)(fEr1 + (size_t)NNODES * 2); // N*32
    float*          fEl2   = (float*)(fH2h + (size_t)NNODES * 32);   // N
    float*          fEr2   = fEl2 + (size_t)NNODES;          // N

    // ---- CSR build + W1^T prep ----
    hipMemsetAsync(ideg, 0, (NNODES + 4) * sizeof(int), stream);
    hist_kernel<<<(NEDGES + 255) / 256, 256, 0, stream>>>(dst, ideg);
    alloc_kernel<<<(NNODES + 255) / 256, 256, 0, stream>>>(ideg, itot, irow, icur);
    fill_kernel<<<(NEDGES + 255) / 256, 256, 0, stream>>>(src, dst, icur, icsr16);
    w1t_kernel<<<32, 256, 0, stream>>>(W1, iw1t);

    // ---- layer 1 ----
    gemm1_kernel<<<(NNODES + 63) / 64, 256, 0, stream>>>(feat, iw1t, al1, ar1,
                                                         fH1h, fEl1, fEr1);
    aggregate1_kernel<<<(NNODES + 3) / 4, 256, 0, stream>>>(
        irow, ideg, icsr16, fEl1, fEr1, fH1h, b1, fH1);

    // ---- layer 2 ----
    gemm2_kernel<<<(NNODES + 127) / 128, 256, 0, stream>>>(fH1, W2, al2, ar2,
                                                           fH2h, fEl2, fEr2);
    aggregate2_kernel<<<(NNODES / 2 + 3) / 4, 256, 0, stream>>>(
        irow, ideg, icsr16, fEl2, fEr2, fH2h, b2, fH1, out);
}

// Round 16
// 279.461 us; speedup vs baseline: 1.2906x; 1.0604x over previous
//
#include <hip/hip_runtime.h>
#include <math.h>

// Problem constants: N=50000, E=800000, IN=128, OUT=64, H1=2, H2=1
#define NNODES 50000
#define NEDGES 800000

typedef short bf16x8 __attribute__((ext_vector_type(8)));
typedef float f32x4  __attribute__((ext_vector_type(4)));

// ---- manual bf16 pack/unpack (plain uint words) ----
__device__ __forceinline__ unsigned bfpack(float a, float b) {
    unsigned ua = __float_as_uint(a), ub = __float_as_uint(b);
    ua = (ua + 0x7fffu + ((ua >> 16) & 1u)) >> 16;
    ub = (ub + 0x7fffu + ((ub >> 16) & 1u)) >> 16;
    return ua | (ub << 16);
}
__device__ __forceinline__ float bflo(unsigned u) { return __uint_as_float(u << 16); }
__device__ __forceinline__ float bfhi(unsigned u) { return __uint_as_float(u & 0xffff0000u); }

// ---------------- CSR build (by dst; shared by both layers) ----------------

__global__ __launch_bounds__(256) void hist_kernel(const int* __restrict__ dst,
                                                   int* __restrict__ deg) {
    int e = blockIdx.x * 256 + threadIdx.x;
    if (e < NEDGES) atomicAdd(&deg[dst[e]], 1);
}

__global__ __launch_bounds__(256) void alloc_kernel(const int* __restrict__ deg,
                                                    int* __restrict__ total,
                                                    int* __restrict__ rowptr,
                                                    int* __restrict__ cursor) {
    const int i = blockIdx.x * 256 + threadIdx.x;
    const int lane = threadIdx.x & 63;
    int d = (i < NNODES) ? deg[i] : 0;
    int incl = d;
#pragma unroll
    for (int off = 1; off < 64; off <<= 1) {
        int t = __shfl_up(incl, off);
        if (lane >= off) incl += t;
    }
    int base = 0;
    if (lane == 63) base = atomicAdd(total, incl);
    base = __shfl(base, 63);
    if (i < NNODES) {
        int pos = base + incl - d;
        rowptr[i] = pos;
        cursor[i] = pos;
    }
}

__global__ __launch_bounds__(256) void fill_kernel(
    const int* __restrict__ src, const int* __restrict__ dst,
    int* __restrict__ cursor, unsigned short* __restrict__ csr_src) {
    int e = blockIdx.x * 256 + threadIdx.x;
    if (e < NEDGES) {
        int pos = atomicAdd(&cursor[dst[e]], 1);
        csr_src[pos] = (unsigned short)src[e];
    }
}

// ---------------- weight prep: W1^T and W2^T packed bf16 -------------------
// W1t [n][64 words], n<128: word j = k-pair (2j,2j+1) of W1[k][n]
// W2t [n][64 words], n<64:  word j = k-pair (2j,2j+1) of W2[k][n]
__global__ __launch_bounds__(256) void wt_kernel(const float* __restrict__ W1,
                                                 const float* __restrict__ W2,
                                                 unsigned* __restrict__ W1t,
                                                 unsigned* __restrict__ W2t) {
    int w = blockIdx.x * 256 + threadIdx.x;   // 0..12287
    if (w < 8192) {
        int n = w >> 6, j = w & 63;
        W1t[w] = bfpack(W1[(2 * j) * 128 + n], W1[(2 * j + 1) * 128 + n]);
    } else {
        int w2 = w - 8192;
        int n = w2 >> 6, j = w2 & 63;
        W2t[w2] = bfpack(W2[(2 * j) * 64 + n], W2[(2 * j + 1) * 64 + n]);
    }
}

// ---------------- gemm1: MFMA bf16 (R15-proven) ----------------
// h(N,128) = feat(N,128) @ W1(128,128) via mfma_f32_16x16x32_bf16.
// A-op: [m=lane&15][k=quad*8+j]; B-op: [n=lane&15][k=quad*8+j] (W^T rows);
// C/D: col=lane&15, row=quad*4+reg.
__global__ __launch_bounds__(256) void gemm1_kernel(
    const float* __restrict__ feat, const unsigned* __restrict__ Wt,
    const float* __restrict__ al, const float* __restrict__ ar,
    unsigned* __restrict__ h, float* __restrict__ el, float* __restrict__ er) {
    __shared__ unsigned Wb[128 * 68];
    __shared__ unsigned Ab[64 * 68];
    const int tid = threadIdx.x;
    const int n0  = blockIdx.x * 64;

#pragma unroll
    for (int i = 0; i < 8; ++i) {
        int id = i * 256 + tid;
        int n = id >> 4, c = (id & 15) * 4;
        *(uint4*)&Wb[n * 68 + c] = *(const uint4*)&Wt[n * 64 + c];
    }
#pragma unroll
    for (int i = 0; i < 8; ++i) {
        int f = i * 256 + tid;
        int m = f >> 5, cf = (f & 31) * 4;
        float4 v = make_float4(0.f, 0.f, 0.f, 0.f);
        if (n0 + m < NNODES)
            v = *(const float4*)&feat[(size_t)(n0 + m) * 128 + cf];
        uint2 p = {bfpack(v.x, v.y), bfpack(v.z, v.w)};
        *(uint2*)&Ab[m * 68 + cf / 2] = p;
    }
    __syncthreads();

    const int w  = tid >> 6;
    const int l  = tid & 63;
    const int ml = l & 15;
    const int q  = l >> 4;
    f32x4 acc[8];
#pragma unroll
    for (int t = 0; t < 8; ++t) acc[t] = (f32x4){0.f, 0.f, 0.f, 0.f};

#pragma unroll
    for (int kc = 0; kc < 4; ++kc) {
        const int kw = kc * 16 + q * 4;
        uint4 a4 = *(uint4*)&Ab[(16 * w + ml) * 68 + kw];
        bf16x8 af = *(bf16x8*)&a4;
#pragma unroll
        for (int t = 0; t < 8; ++t) {
            uint4 b4 = *(uint4*)&Wb[(t * 16 + ml) * 68 + kw];
            bf16x8 bf = *(bf16x8*)&b4;
            acc[t] = __builtin_amdgcn_mfma_f32_16x16x32_bf16(af, bf, acc[t], 0, 0, 0);
        }
    }

    float av[8], rv[8];
#pragma unroll
    for (int t = 0; t < 8; ++t) { av[t] = al[t * 16 + ml]; rv[t] = ar[t * 16 + ml]; }

#pragma unroll
    for (int r = 0; r < 4; ++r) {
        const int node = n0 + 16 * w + q * 4 + r;
        float e0 = 0.f, e1 = 0.f, f0 = 0.f, f1 = 0.f;
#pragma unroll
        for (int t = 0; t < 8; ++t) {
            float v = acc[t][r];
            if (t < 4) { e0 = fmaf(v, av[t], e0); f0 = fmaf(v, rv[t], f0); }
            else       { e1 = fmaf(v, av[t], e1); f1 = fmaf(v, rv[t], f1); }
            float pv = __shfl_xor(v, 1);
            if ((ml & 1) == 0 && node < NNODES)
                h[(size_t)node * 64 + t * 8 + (ml >> 1)] = bfpack(v, pv);
        }
#pragma unroll
        for (int mm = 1; mm <= 8; mm <<= 1) {
            e0 += __shfl_xor(e0, mm); e1 += __shfl_xor(e1, mm);
            f0 += __shfl_xor(f0, mm); f1 += __shfl_xor(f1, mm);
        }
        if (ml == 0 && node < NNODES) {
            el[node * 2 + 0] = e0; el[node * 2 + 1] = e1;
            er[node * 2 + 0] = f0; er[node * 2 + 1] = f1;
        }
    }
}

// ---------------- gemm2: MFMA bf16 (same pattern, 64 cols) -----------------
// h2(N,64) = h1(N,128) @ W2(128,64); fused el2/er2 (H=1).
__global__ __launch_bounds__(256) void gemm2_kernel(
    const float* __restrict__ h1, const unsigned* __restrict__ Wt,
    const float* __restrict__ al, const float* __restrict__ ar,
    unsigned* __restrict__ h2, float* __restrict__ el, float* __restrict__ er) {
    __shared__ unsigned Wb[64 * 68];
    __shared__ unsigned Ab[64 * 68];
    const int tid = threadIdx.x;
    const int n0  = blockIdx.x * 64;

    // stage W2^T: 4096 words = 1024 uint4
#pragma unroll
    for (int i = 0; i < 4; ++i) {
        int id = i * 256 + tid;
        int n = id >> 4, c = (id & 15) * 4;
        *(uint4*)&Wb[n * 68 + c] = *(const uint4*)&Wt[n * 64 + c];
    }
    // stage A (h1 fp32 -> bf16): 2048 float4
#pragma unroll
    for (int i = 0; i < 8; ++i) {
        int f = i * 256 + tid;
        int m = f >> 5, cf = (f & 31) * 4;
        float4 v = make_float4(0.f, 0.f, 0.f, 0.f);
        if (n0 + m < NNODES)
            v = *(const float4*)&h1[(size_t)(n0 + m) * 128 + cf];
        uint2 p = {bfpack(v.x, v.y), bfpack(v.z, v.w)};
        *(uint2*)&Ab[m * 68 + cf / 2] = p;
    }
    __syncthreads();

    const int w  = tid >> 6;
    const int l  = tid & 63;
    const int ml = l & 15;
    const int q  = l >> 4;
    f32x4 acc[4];
#pragma unroll
    for (int t = 0; t < 4; ++t) acc[t] = (f32x4){0.f, 0.f, 0.f, 0.f};

#pragma unroll
    for (int kc = 0; kc < 4; ++kc) {
        const int kw = kc * 16 + q * 4;
        uint4 a4 = *(uint4*)&Ab[(16 * w + ml) * 68 + kw];
        bf16x8 af = *(bf16x8*)&a4;
#pragma unroll
        for (int t = 0; t < 4; ++t) {
            uint4 b4 = *(uint4*)&Wb[(t * 16 + ml) * 68 + kw];
            bf16x8 bf = *(bf16x8*)&b4;
            acc[t] = __builtin_amdgcn_mfma_f32_16x16x32_bf16(af, bf, acc[t], 0, 0, 0);
        }
    }

    float av[4], rv[4];
#pragma unroll
    for (int t = 0; t < 4; ++t) { av[t] = al[t * 16 + ml]; rv[t] = ar[t * 16 + ml]; }

#pragma unroll
    for (int r = 0; r < 4; ++r) {
        const int node = n0 + 16 * w + q * 4 + r;
        float e0 = 0.f, f0 = 0.f;
#pragma unroll
        for (int t = 0; t < 4; ++t) {
            float v = acc[t][r];
            e0 = fmaf(v, av[t], e0);
            f0 = fmaf(v, rv[t], f0);
            float pv = __shfl_xor(v, 1);
            if ((ml & 1) == 0 && node < NNODES)
                h2[(size_t)node * 32 + t * 8 + (ml >> 1)] = bfpack(v, pv);
        }
#pragma unroll
        for (int mm = 1; mm <= 8; mm <<= 1) {
            e0 += __shfl_xor(e0, mm);
            f0 += __shfl_xor(f0, mm);
        }
        if (ml == 0 && node < NNODES) { el[node] = e0; er[node] = f0; }
    }
}

// ---- layer-1 aggregate: ONE wave per node, FOUR edges per gather iter -----
__global__ __launch_bounds__(256) void aggregate1_kernel(
    const int* __restrict__ rowptr, const int* __restrict__ degv,
    const unsigned short* __restrict__ csr_src,
    const float* __restrict__ el, const float* __restrict__ er,
    const unsigned* __restrict__ hh, const float* __restrict__ bias,
    float* __restrict__ outp) {
    const int node = (blockIdx.x * 256 + threadIdx.x) >> 6;
    const int lane = threadIdx.x & 63;
    if (node >= NNODES) return;
    const int row = rowptr[node];
    const int deg = degv[node];
    const float er0 = er[node * 2 + 0];
    const float er1 = er[node * 2 + 1];

    int   s_reg = 0;
    float v0 = -1e30f, v1 = -1e30f;
    if (lane < deg) {
        s_reg = (int)csr_src[row + lane];
        float2 e = *(const float2*)&el[s_reg * 2];
        float a = e.x + er0; v0 = a > 0.f ? a : 0.2f * a;
        float b = e.y + er1; v1 = b > 0.f ? b : 0.2f * b;
    }
    float m0 = v0, m1 = v1;
    for (int i = 64 + lane; i < deg; i += 64) {
        int s = (int)csr_src[row + i];
        float2 e = *(const float2*)&el[s * 2];
        float a = e.x + er0; a = a > 0.f ? a : 0.2f * a;
        float b = e.y + er1; b = b > 0.f ? b : 0.2f * b;
        m0 = fmaxf(m0, a); m1 = fmaxf(m1, b);
    }
#pragma unroll
    for (int off = 32; off > 0; off >>= 1) {
        m0 = fmaxf(m0, __shfl_xor(m0, off));
        m1 = fmaxf(m1, __shfl_xor(m1, off));
    }

    float p0 = (lane < deg) ? __expf(v0 - m0) : 0.f;
    float p1 = (lane < deg) ? __expf(v1 - m1) : 0.f;
    float ssum0 = p0, ssum1 = p1;
    for (int i = 64 + lane; i < deg; i += 64) {
        int s = (int)csr_src[row + i];
        float2 e = *(const float2*)&el[s * 2];
        float a = e.x + er0; a = a > 0.f ? a : 0.2f * a;
        float b = e.y + er1; b = b > 0.f ? b : 0.2f * b;
        ssum0 += __expf(a - m0); ssum1 += __expf(b - m1);
    }
#pragma unroll
    for (int off = 32; off > 0; off >>= 1) {
        ssum0 += __shfl_xor(ssum0, off);
        ssum1 += __shfl_xor(ssum1, off);
    }

    const int  q     = lane >> 4;
    const int  ql    = lane & 15;
    const bool h1sel = (ql >= 8);
    float a0r = 0.f, a1r = 0.f, a2r = 0.f, a3r = 0.f;
    float a4r = 0.f, a5r = 0.f, a6r = 0.f, a7r = 0.f;
    const int dmax = deg < 64 ? deg : 64;
    for (int i = 0; i < dmax; i += 4) {
        int eidx = i + q;
        int esafe = eidx & 63;
        int   s  = __shfl(s_reg, esafe);
        float p0s = __shfl(p0, esafe);
        float p1s = __shfl(p1, esafe);
        if (eidx < dmax) {
            float alpha = h1sel ? p1s : p0s;
            uint4 hv = *(const uint4*)&hh[(size_t)s * 64 + 4 * ql];
            a0r = fmaf(alpha, bflo(hv.x), a0r);
            a1r = fmaf(alpha, bfhi(hv.x), a1r);
            a2r = fmaf(alpha, bflo(hv.y), a2r);
            a3r = fmaf(alpha, bfhi(hv.y), a3r);
            a4r = fmaf(alpha, bflo(hv.z), a4r);
            a5r = fmaf(alpha, bfhi(hv.z), a5r);
            a6r = fmaf(alpha, bflo(hv.w), a6r);
            a7r = fmaf(alpha, bfhi(hv.w), a7r);
        }
    }
    for (int i = 64; i < deg; i += 4) {
        int eidx = i + q;
        if (eidx < deg) {
            int s = (int)csr_src[row + eidx];
            float2 e = *(const float2*)&el[s * 2];
            float a = e.x + er0; a = a > 0.f ? a : 0.2f * a;
            float b = e.y + er1; b = b > 0.f ? b : 0.2f * b;
            float alpha = h1sel ? __expf(b - m1) : __expf(a - m0);
            uint4 hv = *(const uint4*)&hh[(size_t)s * 64 + 4 * ql];
            a0r = fmaf(alpha, bflo(hv.x), a0r);
            a1r = fmaf(alpha, bfhi(hv.x), a1r);
            a2r = fmaf(alpha, bflo(hv.y), a2r);
            a3r = fmaf(alpha, bfhi(hv.y), a3r);
            a4r = fmaf(alpha, bflo(hv.z), a4r);
            a5r = fmaf(alpha, bfhi(hv.z), a5r);
            a6r = fmaf(alpha, bflo(hv.w), a6r);
            a7r = fmaf(alpha, bfhi(hv.w), a7r);
        }
    }
    a0r += __shfl_xor(a0r, 16);  a1r += __shfl_xor(a1r, 16);
    a2r += __shfl_xor(a2r, 16);  a3r += __shfl_xor(a3r, 16);
    a4r += __shfl_xor(a4r, 16);  a5r += __shfl_xor(a5r, 16);
    a6r += __shfl_xor(a6r, 16);  a7r += __shfl_xor(a7r, 16);
    a0r += __shfl_xor(a0r, 32);  a1r += __shfl_xor(a1r, 32);
    a2r += __shfl_xor(a2r, 32);  a3r += __shfl_xor(a3r, 32);
    a4r += __shfl_xor(a4r, 32);  a5r += __shfl_xor(a5r, 32);
    a6r += __shfl_xor(a6r, 32);  a7r += __shfl_xor(a7r, 32);

    if (lane < 16) {
        float ssum = h1sel ? ssum1 : ssum0;
        if (deg > 0) {
            float inv = 1.f / ssum;
            a0r *= inv; a1r *= inv; a2r *= inv; a3r *= inv;
            a4r *= inv; a5r *= inv; a6r *= inv; a7r *= inv;
        }
        float4 b0 = *(const float4*)&bias[8 * ql];
        float4 b1 = *(const float4*)&bias[8 * ql + 4];
        float o0 = a0r + b0.x, o1 = a1r + b0.y, o2 = a2r + b0.z, o3 = a3r + b0.w;
        float o4 = a4r + b1.x, o5 = a5r + b1.y, o6 = a6r + b1.z, o7 = a7r + b1.w;
        o0 = o0 > 0.f ? o0 : (__expf(o0) - 1.f);
        o1 = o1 > 0.f ? o1 : (__expf(o1) - 1.f);
        o2 = o2 > 0.f ? o2 : (__expf(o2) - 1.f);
        o3 = o3 > 0.f ? o3 : (__expf(o3) - 1.f);
        o4 = o4 > 0.f ? o4 : (__expf(o4) - 1.f);
        o5 = o5 > 0.f ? o5 : (__expf(o5) - 1.f);
        o6 = o6 > 0.f ? o6 : (__expf(o6) - 1.f);
        o7 = o7 > 0.f ? o7 : (__expf(o7) - 1.f);
        *(float4*)&outp[(size_t)node * 128 + 8 * ql]     = make_float4(o0, o1, o2, o3);
        *(float4*)&outp[(size_t)node * 128 + 8 * ql + 4] = make_float4(o4, o5, o6, o7);
    }
}

// ---- layer-2 aggregate: TWO nodes per wave, TWO edges per iter per node ---
__global__ __launch_bounds__(256) void aggregate2_kernel(
    const int* __restrict__ rowptr, const int* __restrict__ degv,
    const unsigned short* __restrict__ csr_src,
    const float* __restrict__ el, const float* __restrict__ er,
    const unsigned* __restrict__ hh, const float* __restrict__ bias,
    const float* __restrict__ h1, float* __restrict__ outp) {
    const int wid  = (blockIdx.x * 256 + threadIdx.x) >> 6;
    const int lane = threadIdx.x & 63;
    const int hl   = lane & 31;
    const int node = wid * 2 + (lane >> 5);
    if (node >= NNODES) return;
    const int row = rowptr[node];
    const int deg = degv[node];
    const float erd = er[node];

    int   s_reg = 0;
    float v_reg = -1e30f;
    if (hl < deg) {
        s_reg = (int)csr_src[row + hl];
        float v = el[s_reg] + erd;
        v_reg = v > 0.f ? v : 0.2f * v;
    }
    float m = v_reg;
    for (int i = 32 + hl; i < deg; i += 32) {
        int s = (int)csr_src[row + i];
        float v = el[s] + erd;
        v = v > 0.f ? v : 0.2f * v;
        m = fmaxf(m, v);
    }
#pragma unroll
    for (int off = 16; off > 0; off >>= 1) m = fmaxf(m, __shfl_xor(m, off));

    float p_reg = (hl < deg) ? __expf(v_reg - m) : 0.f;
    float ssum = p_reg;
    for (int i = 32 + hl; i < deg; i += 32) {
        int s = (int)csr_src[row + i];
        float v = el[s] + erd;
        v = v > 0.f ? v : 0.2f * v;
        ssum += __expf(v - m);
    }
#pragma unroll
    for (int off = 16; off > 0; off >>= 1) ssum += __shfl_xor(ssum, off);

    const int s2 = hl >> 4;
    const int sl = hl & 15;
    float ax = 0.f, ay = 0.f, az = 0.f, aw = 0.f;
    const int dmax = deg < 32 ? deg : 32;
    int dmW = dmax;
    dmW = max(dmW, __shfl_xor(dmW, 32));
    for (int i = 0; i < dmW; i += 2) {
        int eidx = i + s2;
        int esafe = (lane & 32) + (eidx & 31);
        int   s = __shfl(s_reg, esafe);
        float p = __shfl(p_reg, esafe);
        if (eidx < dmax) {
            uint2 hv = *(const uint2*)&hh[(size_t)s * 32 + 2 * sl];
            ax = fmaf(p, bflo(hv.x), ax);
            ay = fmaf(p, bfhi(hv.x), ay);
            az = fmaf(p, bflo(hv.y), az);
            aw = fmaf(p, bfhi(hv.y), aw);
        }
    }
    for (int i = 32; i < deg; i += 2) {
        int eidx = i + s2;
        if (eidx < deg) {
            int s = (int)csr_src[row + eidx];
            float v = el[s] + erd;
            v = v > 0.f ? v : 0.2f * v;
            float p = __expf(v - m);
            uint2 hv = *(const uint2*)&hh[(size_t)s * 32 + 2 * sl];
            ax = fmaf(p, bflo(hv.x), ax);
            ay = fmaf(p, bfhi(hv.x), ay);
            az = fmaf(p, bflo(hv.y), az);
            aw = fmaf(p, bfhi(hv.y), aw);
        }
    }
    ax += __shfl_xor(ax, 16);  ay += __shfl_xor(ay, 16);
    az += __shfl_xor(az, 16);  aw += __shfl_xor(aw, 16);

    if (sl == hl) {
        if (deg > 0) {
            float inv = 1.f / ssum;
            ax *= inv; ay *= inv; az *= inv; aw *= inv;
        }
        float4 hA = *(const float4*)&h1[(size_t)node * 128 + 4 * sl];
        float4 hB = *(const float4*)&h1[(size_t)node * 128 + 64 + 4 * sl];
        float4 bb = *(const float4*)&bias[4 * sl];
        float o0 = ((hA.x + hB.x) * 0.5f + ax + bb.x) * 0.5f;
        float o1 = ((hA.y + hB.y) * 0.5f + ay + bb.y) * 0.5f;
        float o2 = ((hA.z + hB.z) * 0.5f + az + bb.z) * 0.5f;
        float o3 = ((hA.w + hB.w) * 0.5f + aw + bb.w) * 0.5f;
        *(float4*)&outp[(size_t)node * 64 + 4 * sl] = make_float4(o0, o1, o2, o3);
    }
}

// ---------------- launcher ----------------

extern "C" void kernel_launch(void* const* d_in, const int* in_sizes, int n_in,
                              void* d_out, int out_size, void* d_ws, size_t ws_size,
                              hipStream_t stream) {
    const float* feat = (const float*)d_in[0];
    const int*   src  = (const int*)d_in[1];
    const int*   dst  = (const int*)d_in[2];
    const float* W1   = (const float*)d_in[3];
    const float* al1  = (const float*)d_in[4];
    const float* ar1  = (const float*)d_in[5];
    const float* b1   = (const float*)d_in[6];
    const float* W2   = (const float*)d_in[7];
    const float* al2  = (const float*)d_in[8];
    const float* ar2  = (const float*)d_in[9];
    const float* b2   = (const float*)d_in[10];
    float* out = (float*)d_out;

    // workspace layout (4-byte units; ~48 MB total, 16B-aligned sections)
    int*            ideg   = (int*)d_ws;                     // N
    int*            itot   = ideg + NNODES;                  // 4
    int*            irow   = itot + 4;                       // N
    int*            icur   = irow + NNODES;                  // N
    unsigned*       iw1t   = (unsigned*)(icur + NNODES);     // 8192 (W1^T bf16)
    unsigned*       iw2t   = iw1t + 8192;                    // 4096 (W2^T bf16)
    unsigned short* icsr16 = (unsigned short*)(iw2t + 4096); // E ushorts
    unsigned*       fH1h   = (unsigned*)(iw2t + 4096 + NEDGES / 2); // N*64 uints
    float*          fH1    = (float*)(fH1h + (size_t)NNODES * 64);  // N*128
    float*          fEl1   = fH1  + (size_t)NNODES * 128;    // N*2
    float*          fEr1   = fEl1 + (size_t)NNODES * 2;      // N*2
    unsigned*       fH2h   = (unsigned*)(fEr1 + (size_t)NNODES * 2); // N*32
    float*          fEl2   = (float*)(fH2h + (size_t)NNODES * 32);   // N
    float*          fEr2   = fEl2 + (size_t)NNODES;          // N

    // ---- CSR build + weight prep ----
    hipMemsetAsync(ideg, 0, (NNODES + 4) * sizeof(int), stream);
    hist_kernel<<<(NEDGES + 255) / 256, 256, 0, stream>>>(dst, ideg);
    alloc_kernel<<<(NNODES + 255) / 256, 256, 0, stream>>>(ideg, itot, irow, icur);
    fill_kernel<<<(NEDGES + 255) / 256, 256, 0, stream>>>(src, dst, icur, icsr16);
    wt_kernel<<<48, 256, 0, stream>>>(W1, W2, iw1t, iw2t);

    // ---- layer 1 ----
    gemm1_kernel<<<(NNODES + 63) / 64, 256, 0, stream>>>(feat, iw1t, al1, ar1,
                                                         fH1h, fEl1, fEr1);
    aggregate1_kernel<<<(NNODES + 3) / 4, 256, 0, stream>>>(
        irow, ideg, icsr16, fEl1, fEr1, fH1h, b1, fH1);

    // ---- layer 2 ----
    gemm2_kernel<<<(NNODES + 63) / 64, 256, 0, stream>>>(fH1, iw2t, al2, ar2,
                                                         fH2h, fEl2, fEr2);
    aggregate2_kernel<<<(NNODES / 2 + 3) / 4, 256, 0, stream>>>(
        irow, ideg, icsr16, fEl2, fEr2, fH2h, b2, fH1, out);
}